// Round 8
// baseline (445.744 us; speedup 1.0000x reference)
//
#include <hip/hip_runtime.h>
#include <hip/hip_bf16.h>

#define EPSF 1e-5f
#define IOU_THRF 0.9f
#define NBOX 9216
#define NWORDS 144   // 9216/64
#define CAND_CAP 4096
#define FIRE_CAP 1024
#define NTILES 666   // 36*37/2 upper-tri 256x256 tiles

// ---------------- depthwise 3x3 conv, C=256, 32x32, pad 1 ----------------
__global__ __launch_bounds__(256) void dw_conv(const float* __restrict__ x,
                                               const float* __restrict__ w,
                                               float* __restrict__ h0) {
    int idx = blockIdx.x * 256 + threadIdx.x;   // 262144 threads
    int c = idx >> 10, p = idx & 1023;
    int yy = p >> 5, xx = p & 31;
    const float* xi = x + (c << 10);
    const float* wc = w + c * 9;
    float acc = 0.f;
    #pragma unroll
    for (int dy = -1; dy <= 1; ++dy) {
        int y2 = yy + dy;
        if ((unsigned)y2 >= 32u) continue;
        #pragma unroll
        for (int dx = -1; dx <= 1; ++dx) {
            int x2 = xx + dx;
            if ((unsigned)x2 >= 32u) continue;
            acc += wc[(dy + 1) * 3 + (dx + 1)] * xi[y2 * 32 + x2];
        }
    }
    h0[idx] = acc;
}

// ---------------- pointwise 256x256 GEMM + BN1 + leaky relu ----------------
__global__ __launch_bounds__(256) void pw_conv(const float* __restrict__ h0,
                                               const float* __restrict__ w,
                                               const float* __restrict__ g,
                                               const float* __restrict__ b,
                                               const float* __restrict__ mu,
                                               const float* __restrict__ var,
                                               float* __restrict__ h1) {
    int p = blockIdx.x * 256 + threadIdx.x;
    int o0 = blockIdx.y * 4;
    float acc0 = 0.f, acc1 = 0.f, acc2 = 0.f, acc3 = 0.f;
    for (int c = 0; c < 256; ++c) {
        float hv = h0[(c << 10) + p];
        acc0 += w[(o0 + 0) * 256 + c] * hv;
        acc1 += w[(o0 + 1) * 256 + c] * hv;
        acc2 += w[(o0 + 2) * 256 + c] * hv;
        acc3 += w[(o0 + 3) * 256 + c] * hv;
    }
    float accs[4] = {acc0, acc1, acc2, acc3};
    #pragma unroll
    for (int k = 0; k < 4; ++k) {
        int o = o0 + k;
        float inv = 1.0f / sqrtf(var[o] + EPSF);
        float v = (accs[k] - mu[o]) * (inv * g[o]) + b[o];
        v = (v >= 0.f) ? v : 0.01f * v;
        h1[(o << 10) + p] = v;
    }
}

// ---------------- heads: anc (36 ch) + obj (9 ch) GEMV + BN + decode ----------------
__global__ __launch_bounds__(256) void heads(const float* __restrict__ h1,
                                             const float* __restrict__ anc_w,
                                             const float* __restrict__ ag,
                                             const float* __restrict__ ab,
                                             const float* __restrict__ am,
                                             const float* __restrict__ av,
                                             const float* __restrict__ obj_w,
                                             const float* __restrict__ og,
                                             const float* __restrict__ ob,
                                             const float* __restrict__ om,
                                             const float* __restrict__ ov,
                                             const float* __restrict__ anchors,
                                             float* __restrict__ boxes,
                                             float* __restrict__ scores) {
    int p = blockIdx.x * 256 + threadIdx.x;
    int o = blockIdx.y;
    const float* wrow = (o < 36) ? (anc_w + o * 256) : (obj_w + (o - 36) * 256);
    float acc = 0.f;
    for (int c = 0; c < 256; ++c) acc += wrow[c] * h1[(c << 10) + p];
    if (o < 36) {
        float inv = 1.0f / sqrtf(av[o] + EPSF);
        float v = (acc - am[o]) * (inv * ag[o]) + ab[o];
        v = fminf(fmaxf(v, 0.f), 6.f);           // clip 0..6
        int a = o >> 2, k = o & 3;
        float anch = anchors[a * 4 + k];
        float val = (k < 2) ? (v + anch) : (expf(v) * anch);
        boxes[(size_t)(a * 1024 + p) * 4 + k] = val;
    } else {
        int a = o - 36;
        float inv = 1.0f / sqrtf(ov[a] + EPSF);
        float v = (acc - om[a]) * (inv * og[a]) + ob[a];
        scores[a * 1024 + p] = 1.0f / (1.0f + expf(-v));
    }
}

// ---------------- rank = stable-descending-argsort position, O(N^2) count ----------------
__global__ __launch_bounds__(256) void rank_partial(const float* __restrict__ scores,
                                                    unsigned* __restrict__ rank) {
    __shared__ float4 sm[288];
    int mbase = blockIdx.y * 1152;
    for (int t = threadIdx.x; t < 288; t += 256)
        sm[t] = ((const float4*)(scores + mbase))[t];
    __syncthreads();
    int n = blockIdx.x * 256 + threadIdx.x;
    float s = scores[n];
    unsigned cnt = 0;
    for (int q = 0; q < 288; ++q) {
        float4 v = sm[q];
        int m = mbase + q * 4;
        cnt += (v.x > s) || (v.x == s && (m + 0) < n);
        cnt += (v.y > s) || (v.y == s && (m + 1) < n);
        cnt += (v.z > s) || (v.z == s && (m + 2) < n);
        cnt += (v.w > s) || (v.w == s && (m + 3) < n);
    }
    atomicAdd(&rank[n], cnt);
}

// ---------------- scatter into sorted order ----------------
__global__ __launch_bounds__(256) void scatter_sorted(const float* __restrict__ boxes,
                                                      const unsigned* __restrict__ rank,
                                                      int* __restrict__ order,
                                                      float* __restrict__ sboxes,
                                                      float* __restrict__ sareas) {
    int n = blockIdx.x * 256 + threadIdx.x;
    unsigned r = rank[n];
    order[r] = n;
    float4 bx = ((const float4*)boxes)[n];
    ((float4*)sboxes)[r] = bx;
    sareas[r] = (bx.z - bx.x) * (bx.w - bx.y);
}

// ---------------- candidate detection over upper-tri 256x256 tiles ----------------
__global__ __launch_bounds__(256) void cand_detect(const float* __restrict__ sboxes,
                                                   const float* __restrict__ sareas,
                                                   unsigned long long* __restrict__ rnz64) {
    __shared__ float CX1[256], CY1[256], CX2[256], CY2[256], CAR[256];
    int rem = blockIdx.x, rb = 0;
    while (rem >= 36 - rb) { rem -= 36 - rb; ++rb; }
    int s = rb + rem;
    int tid = threadIdx.x;
    int i = rb * 256 + tid;
    {
        int j = s * 256 + tid;
        float4 cb = ((const float4*)sboxes)[j];
        CX1[tid] = cb.x; CY1[tid] = cb.y; CX2[tid] = cb.z; CY2[tid] = cb.w;
        CAR[tid] = sareas[j];
    }
    __syncthreads();
    float4 b = ((const float4*)sboxes)[i];
    float ar = sareas[i];
    bool any = false;

    if (s == rb) {
        for (int idx = tid + 1; idx < 256; ++idx) {
            float ix = fminf(b.z, CX2[idx]) - fmaxf(b.x, CX1[idx]);
            float iy = fminf(b.w, CY2[idx]) - fmaxf(b.y, CY1[idx]);
            float inter = fmaxf(ix, 0.f) * fmaxf(iy, 0.f);
            float denom = ar + CAR[idx] - inter;
            if (inter > 0.85f * denom) {
                if (inter / denom > IOU_THRF) any = true;
            }
        }
    } else {
        const float4* X1v = (const float4*)CX1;
        const float4* Y1v = (const float4*)CY1;
        const float4* X2v = (const float4*)CX2;
        const float4* Y2v = (const float4*)CY2;
        const float4* ARv = (const float4*)CAR;
        #pragma unroll 2
        for (int q = 0; q < 64; ++q) {
            float4 x1 = X1v[q], y1 = Y1v[q], x2 = X2v[q], y2 = Y2v[q], aa = ARv[q];
            #define CCHK(k) { \
                float ix = fminf(b.z, x2.k) - fmaxf(b.x, x1.k); \
                float iy = fminf(b.w, y2.k) - fmaxf(b.y, y1.k); \
                float inter = fmaxf(ix, 0.f) * fmaxf(iy, 0.f);  \
                float denom = ar + aa.k - inter;                \
                if (inter > 0.85f * denom) {                    \
                    if (inter / denom > IOU_THRF) any = true;   \
                } }
            CCHK(x) CCHK(y) CCHK(z) CCHK(w)
            #undef CCHK
        }
    }
    unsigned long long bal = __ballot(any);
    if ((tid & 63) == 0) atomicOr(&rnz64[rb * 4 + (tid >> 6)], bal);
}

__device__ inline unsigned long long rdl64(unsigned long long v, int l) {
    unsigned lo = (unsigned)__builtin_amdgcn_readlane((int)(unsigned)(v & 0xffffffffull), l);
    unsigned hi = (unsigned)__builtin_amdgcn_readlane((int)(unsigned)(v >> 32), l);
    return ((unsigned long long)hi << 32) | lo;
}

// ---------------- compact candidates (order-preserving), 1 wave, registers only ----------------
__global__ __launch_bounds__(64) void compact_cand(const unsigned long long* __restrict__ rnz64,
                                                   const float* __restrict__ sboxes,
                                                   const float* __restrict__ sareas,
                                                   int* __restrict__ cidx,
                                                   float4* __restrict__ cboxes,
                                                   float* __restrict__ carea,
                                                   int* __restrict__ knum) {
    int lane = threadIdx.x;
    // preload all 144 words (padded to 192) into 3 registers — no loads in loop
    unsigned long long rz0 = rnz64[lane];
    unsigned long long rz1 = rnz64[64 + lane];
    unsigned long long rz2 = rnz64[128 + lane];
    int base = 0;
    for (int w = 0; w < NWORDS; ++w) {
        unsigned long long bits = (w < 64) ? rdl64(rz0, w)
                                : (w < 128) ? rdl64(rz1, w - 64) : rdl64(rz2, w - 128);
        if (bits & (1ull << lane)) {
            int pos = base + (int)__popcll(bits & ((1ull << lane) - 1ull));
            if (pos < CAND_CAP) {
                int i = w * 64 + lane;
                cidx[pos] = i;
                cboxes[pos] = ((const float4*)sboxes)[i];
                carea[pos] = sareas[i];
            }
        }
        base += (int)__popcll(bits);
    }
    if (lane == 0) knum[0] = base < CAND_CAP ? base : CAND_CAP;
}

// ---------------- candidate x candidate gating matrix + diagonal strips ----------------
__global__ __launch_bounds__(256) void gate_build(const float4* __restrict__ cboxes,
                                                  const float* __restrict__ carea,
                                                  const int* __restrict__ knum,
                                                  unsigned long long* __restrict__ gate,
                                                  unsigned long long* __restrict__ diag0,
                                                  unsigned long long* __restrict__ diag1) {
    int Kc = knum[0];
    int a = blockIdx.x * 4 + (threadIdx.x >> 6);
    int w = threadIdx.x & 63;
    if (a >= Kc) return;
    float4 b = cboxes[a];
    float ar = carea[a];
    unsigned long long bits = 0ull;
    int cbase = w * 64;
    if (cbase < Kc) {
        int lim = Kc - cbase; if (lim > 64) lim = 64;
        for (int t = 0; t < lim; ++t) {
            int c = cbase + t;
            if (c > a) {
                float4 cb = cboxes[c];
                float ix = fminf(b.z, cb.z) - fmaxf(b.x, cb.x);
                float iy = fminf(b.w, cb.w) - fmaxf(b.y, cb.y);
                float inter = fmaxf(ix, 0.f) * fmaxf(iy, 0.f);
                float denom = ar + carea[c] - inter;
                if (inter > 0.85f * denom) {
                    if (inter / denom > IOU_THRF) bits |= (1ull << t);
                }
            }
        }
    }
    gate[(size_t)a * 64 + w] = bits;
    int aw = a >> 6;
    if (w == aw) diag0[a] = bits;           // within-word strip
    if (w == aw + 1) diag1[a] = bits;       // next-word strip
}

// ---------------- serial greedy scan: registers strips + 2-generation delayed drain ----------------
__global__ __launch_bounds__(64) void nms_scan2(const unsigned long long* __restrict__ gate,
                                                const unsigned long long* __restrict__ diag0,
                                                const unsigned long long* __restrict__ diag1,
                                                const int* __restrict__ knum,
                                                int* __restrict__ fire_ord,
                                                int* __restrict__ fire_cnt) {
    int lane = threadIdx.x;
    int Kc = knum[0];
    int nw = (Kc + 63) >> 6;
    unsigned long long sup = 0ull;     // lane l owns candidate word l (retired fires only)
    unsigned long long carry = 0ull;   // uniform: prev-word fires' bits for CURRENT word
    int nf = 0;

    // pending fire rows: generation A (fires from word w), B (from word w-1, drains at w+1)
    unsigned long long qa0=0,qa1=0,qa2=0,qa3=0,qa4=0,qa5=0,qa6=0,qa7=0; int nA = 0;
    unsigned long long qb0=0,qb1=0,qb2=0,qb3=0,qb4=0,qb5=0,qb6=0,qb7=0; int nB = 0;

    // diag strips, prefetched 2 words ahead (lane t holds strip entry of ordinal w*64+t)
    unsigned long long d0A = diag0[lane], d0B = diag0[64 + lane];
    unsigned long long d1A = diag1[lane], d1B = diag1[64 + lane];

    for (int w = 0; w < nw; ++w) {
        int pf = (w + 2) * 64 + lane;          // diag arrays padded past CAND_CAP
        unsigned long long d0C = diag0[pf];
        unsigned long long d1C = diag1[pf];

        // drain generation B (fires from word w-2; loads are 2 iterations old)
        if (nB > 0) { sup |= qb0;
            if (nB > 1) sup |= qb1; if (nB > 2) sup |= qb2; if (nB > 3) sup |= qb3;
            if (nB > 4) sup |= qb4; if (nB > 5) sup |= qb5; if (nB > 6) sup |= qb6;
            if (nB > 7) sup |= qb7; }
        qb0=qa0; qb1=qa1; qb2=qa2; qb3=qa3; qb4=qa4; qb5=qa5; qb6=qa6; qb7=qa7;
        nB = nA; nA = 0;

        int rem = Kc - (w << 6);
        unsigned long long maskw = (rem >= 64) ? ~0ull : ((1ull << rem) - 1ull);
        unsigned long long alive = ~(rdl64(sup, w) | carry) & maskw;
        unsigned long long carry_next = 0ull;

        while (alive) {
            int t = __builtin_ctzll(alive);
            if (lane == 0 && nf < FIRE_CAP) fire_ord[nf] = (w << 6) + t;
            ++nf;
            unsigned long long g = gate[((size_t)(w << 6) + t) * 64 + lane];  // 512B coalesced
            if (nA == 0) qa0 = g; else if (nA == 1) qa1 = g; else if (nA == 2) qa2 = g;
            else if (nA == 3) qa3 = g; else if (nA == 4) qa4 = g; else if (nA == 5) qa5 = g;
            else if (nA == 6) qa6 = g; else if (nA == 7) qa7 = g;
            else sup |= g;                    // ring overflow: retire now (rare)
            if (nA < 8) ++nA;
            alive &= ~(1ull << t);
            alive &= ~rdl64(d0A, t);          // within-word suppression (register)
            carry_next |= rdl64(d1A, t);      // next-word suppression (register)
        }
        carry = carry_next;
        d0A = d0B; d0B = d0C; d1A = d1B; d1B = d1C;
    }
    if (lane == 0) fire_cnt[0] = nf < FIRE_CAP ? nf : FIRE_CAP;
}

// ---------------- finalize: recompute suppression vs fires, write output ----------------
__global__ __launch_bounds__(256) void finalize(const float* __restrict__ sboxes,
                                                const float* __restrict__ sareas,
                                                const float* __restrict__ scores,
                                                const int* __restrict__ order,
                                                const float4* __restrict__ cboxes,
                                                const float* __restrict__ carea,
                                                const int* __restrict__ cidx,
                                                const int* __restrict__ fire_ord,
                                                const int* __restrict__ fire_cnt,
                                                float* __restrict__ out) {
    __shared__ float4 FB[FIRE_CAP];
    __shared__ float FA[FIRE_CAP];
    __shared__ int FP[FIRE_CAP];
    int tid = threadIdx.x;
    int fc = fire_cnt[0];
    for (int k = tid; k < fc; k += 256) {
        int o = fire_ord[k];
        FB[k] = cboxes[o];
        FA[k] = carea[o];
        FP[k] = cidx[o];
    }
    __syncthreads();
    int j = blockIdx.x * 256 + tid;   // sorted index
    float4 b = ((const float4*)sboxes)[j];
    float aj = sareas[j];
    bool supp = false;
    for (int k = 0; k < fc; ++k) {
        float4 f = FB[k];
        float ix = fminf(b.z, f.z) - fmaxf(b.x, f.x);
        float iy = fminf(b.w, f.w) - fmaxf(b.y, f.y);
        float inter = fmaxf(ix, 0.f) * fmaxf(iy, 0.f);
        float denom = FA[k] + aj - inter;
        if (FP[k] < j && inter > 0.85f * denom) {
            if (inter / denom > IOU_THRF) supp = true;
        }
    }
    int n = order[j];
    float m = supp ? 0.f : 1.f;
    out[(size_t)n * 5 + 0] = b.x * m;
    out[(size_t)n * 5 + 1] = b.y * m;
    out[(size_t)n * 5 + 2] = b.z * m;
    out[(size_t)n * 5 + 3] = b.w * m;
    out[(size_t)n * 5 + 4] = scores[n] * m;
}

extern "C" void kernel_launch(void* const* d_in, const int* in_sizes, int n_in,
                              void* d_out, int out_size, void* d_ws, size_t ws_size,
                              hipStream_t stream) {
    const float* x      = (const float*)d_in[0];
    const float* anchors= (const float*)d_in[1];
    const float* dw_w   = (const float*)d_in[2];
    const float* pw_w   = (const float*)d_in[3];
    const float* bn1g   = (const float*)d_in[4];
    const float* bn1b   = (const float*)d_in[5];
    const float* bn1m   = (const float*)d_in[6];
    const float* bn1v   = (const float*)d_in[7];
    const float* anc_w  = (const float*)d_in[8];
    const float* ag     = (const float*)d_in[9];
    const float* ab     = (const float*)d_in[10];
    const float* am     = (const float*)d_in[11];
    const float* av     = (const float*)d_in[12];
    const float* obj_w  = (const float*)d_in[13];
    const float* og     = (const float*)d_in[14];
    const float* ob     = (const float*)d_in[15];
    const float* om     = (const float*)d_in[16];
    const float* ov     = (const float*)d_in[17];
    float* out = (float*)d_out;

    char* ws = (char*)d_ws;
    size_t off = 0;
    auto alloc = [&](size_t bytes) -> char* {
        char* p = ws + off;
        off = (off + bytes + 255) & ~(size_t)255;
        return p;
    };
    float* h0      = (float*)alloc(256 * 1024 * 4);
    float* h1      = (float*)alloc(256 * 1024 * 4);
    float* boxes   = (float*)alloc(NBOX * 4 * 4);
    float* scores  = (float*)alloc(NBOX * 4);
    unsigned* rank = (unsigned*)alloc(NBOX * 4);
    int* order     = (int*)alloc(NBOX * 4);
    float* sboxes  = (float*)alloc(NBOX * 4 * 4);
    float* sareas  = (float*)alloc(NBOX * 4);
    unsigned long long* rnz64 = (unsigned long long*)alloc(192 * 8);
    int* cidx      = (int*)alloc(CAND_CAP * 4);
    float4* cboxes = (float4*)alloc(CAND_CAP * 16);
    float* carea   = (float*)alloc(CAND_CAP * 4);
    int* knum      = (int*)alloc(256);
    int* fire_ord  = (int*)alloc(FIRE_CAP * 4);
    int* fire_cnt  = (int*)alloc(256);
    unsigned long long* gate  = (unsigned long long*)alloc((size_t)CAND_CAP * 64 * 8);
    unsigned long long* diag0 = (unsigned long long*)alloc((CAND_CAP + 192) * 8);
    unsigned long long* diag1 = (unsigned long long*)alloc((CAND_CAP + 192) * 8);

    hipMemsetAsync(rank, 0, NBOX * 4, stream);
    hipMemsetAsync(rnz64, 0, 192 * 8, stream);

    dw_conv<<<1024, 256, 0, stream>>>(x, dw_w, h0);
    pw_conv<<<dim3(4, 64), 256, 0, stream>>>(h0, pw_w, bn1g, bn1b, bn1m, bn1v, h1);
    heads<<<dim3(4, 45), 256, 0, stream>>>(h1, anc_w, ag, ab, am, av,
                                           obj_w, og, ob, om, ov, anchors, boxes, scores);
    rank_partial<<<dim3(36, 8), 256, 0, stream>>>(scores, rank);
    scatter_sorted<<<36, 256, 0, stream>>>(boxes, rank, order, sboxes, sareas);
    cand_detect<<<NTILES, 256, 0, stream>>>(sboxes, sareas, rnz64);
    compact_cand<<<1, 64, 0, stream>>>(rnz64, sboxes, sareas, cidx, cboxes, carea, knum);
    gate_build<<<CAND_CAP / 4, 256, 0, stream>>>(cboxes, carea, knum, gate, diag0, diag1);
    nms_scan2<<<1, 64, 0, stream>>>(gate, diag0, diag1, knum, fire_ord, fire_cnt);
    finalize<<<36, 256, 0, stream>>>(sboxes, sareas, scores, order,
                                     cboxes, carea, cidx, fire_ord, fire_cnt, out);
}

// Round 9
// 432.678 us; speedup vs baseline: 1.0302x; 1.0302x over previous
//
#include <hip/hip_runtime.h>
#include <hip/hip_bf16.h>

#define EPSF 1e-5f
#define IOU_THRF 0.9f
#define NBOX 9216
#define NWORDS 144   // 9216/64
#define CAND_CAP 4096
#define FIRE_CAP 1024
#define NTILES 666   // 36*37/2 upper-tri 256x256 tiles

// ---------------- depthwise 3x3 conv, C=256, 32x32, pad 1 ----------------
__global__ __launch_bounds__(256) void dw_conv(const float* __restrict__ x,
                                               const float* __restrict__ w,
                                               float* __restrict__ h0) {
    int idx = blockIdx.x * 256 + threadIdx.x;   // 262144 threads
    int c = idx >> 10, p = idx & 1023;
    int yy = p >> 5, xx = p & 31;
    const float* xi = x + (c << 10);
    const float* wc = w + c * 9;
    float acc = 0.f;
    #pragma unroll
    for (int dy = -1; dy <= 1; ++dy) {
        int y2 = yy + dy;
        if ((unsigned)y2 >= 32u) continue;
        #pragma unroll
        for (int dx = -1; dx <= 1; ++dx) {
            int x2 = xx + dx;
            if ((unsigned)x2 >= 32u) continue;
            acc += wc[(dy + 1) * 3 + (dx + 1)] * xi[y2 * 32 + x2];
        }
    }
    h0[idx] = acc;
}

// ---------------- pointwise 256x256 GEMM + BN1 + leaky relu ----------------
__global__ __launch_bounds__(256) void pw_conv(const float* __restrict__ h0,
                                               const float* __restrict__ w,
                                               const float* __restrict__ g,
                                               const float* __restrict__ b,
                                               const float* __restrict__ mu,
                                               const float* __restrict__ var,
                                               float* __restrict__ h1) {
    int p = blockIdx.x * 256 + threadIdx.x;
    int o0 = blockIdx.y * 4;
    float acc0 = 0.f, acc1 = 0.f, acc2 = 0.f, acc3 = 0.f;
    for (int c = 0; c < 256; ++c) {
        float hv = h0[(c << 10) + p];
        acc0 += w[(o0 + 0) * 256 + c] * hv;
        acc1 += w[(o0 + 1) * 256 + c] * hv;
        acc2 += w[(o0 + 2) * 256 + c] * hv;
        acc3 += w[(o0 + 3) * 256 + c] * hv;
    }
    float accs[4] = {acc0, acc1, acc2, acc3};
    #pragma unroll
    for (int k = 0; k < 4; ++k) {
        int o = o0 + k;
        float inv = 1.0f / sqrtf(var[o] + EPSF);
        float v = (accs[k] - mu[o]) * (inv * g[o]) + b[o];
        v = (v >= 0.f) ? v : 0.01f * v;
        h1[(o << 10) + p] = v;
    }
}

// ---------------- heads: anc (36 ch) + obj (9 ch) GEMV + BN + decode ----------------
__global__ __launch_bounds__(256) void heads(const float* __restrict__ h1,
                                             const float* __restrict__ anc_w,
                                             const float* __restrict__ ag,
                                             const float* __restrict__ ab,
                                             const float* __restrict__ am,
                                             const float* __restrict__ av,
                                             const float* __restrict__ obj_w,
                                             const float* __restrict__ og,
                                             const float* __restrict__ ob,
                                             const float* __restrict__ om,
                                             const float* __restrict__ ov,
                                             const float* __restrict__ anchors,
                                             float* __restrict__ boxes,
                                             float* __restrict__ scores) {
    int p = blockIdx.x * 256 + threadIdx.x;
    int o = blockIdx.y;
    const float* wrow = (o < 36) ? (anc_w + o * 256) : (obj_w + (o - 36) * 256);
    float acc = 0.f;
    for (int c = 0; c < 256; ++c) acc += wrow[c] * h1[(c << 10) + p];
    if (o < 36) {
        float inv = 1.0f / sqrtf(av[o] + EPSF);
        float v = (acc - am[o]) * (inv * ag[o]) + ab[o];
        v = fminf(fmaxf(v, 0.f), 6.f);           // clip 0..6
        int a = o >> 2, k = o & 3;
        float anch = anchors[a * 4 + k];
        float val = (k < 2) ? (v + anch) : (expf(v) * anch);
        boxes[(size_t)(a * 1024 + p) * 4 + k] = val;
    } else {
        int a = o - 36;
        float inv = 1.0f / sqrtf(ov[a] + EPSF);
        float v = (acc - om[a]) * (inv * og[a]) + ob[a];
        scores[a * 1024 + p] = 1.0f / (1.0f + expf(-v));
    }
}

// ---------------- rank = stable-descending-argsort position, O(N^2) count ----------------
// grid (36 n-blocks, 16 m-chunks of 576), 256 thr
__global__ __launch_bounds__(256) void rank_partial(const float* __restrict__ scores,
                                                    unsigned* __restrict__ rank) {
    __shared__ float4 sm[144];
    int mbase = blockIdx.y * 576;
    for (int t = threadIdx.x; t < 144; t += 256)
        sm[t] = ((const float4*)(scores + mbase))[t];
    __syncthreads();
    int n = blockIdx.x * 256 + threadIdx.x;
    float s = scores[n];
    unsigned cnt = 0;
    for (int q = 0; q < 144; ++q) {
        float4 v = sm[q];
        int m = mbase + q * 4;
        cnt += (v.x > s) || (v.x == s && (m + 0) < n);
        cnt += (v.y > s) || (v.y == s && (m + 1) < n);
        cnt += (v.z > s) || (v.z == s && (m + 2) < n);
        cnt += (v.w > s) || (v.w == s && (m + 3) < n);
    }
    atomicAdd(&rank[n], cnt);
}

// ---------------- scatter into sorted order ----------------
__global__ __launch_bounds__(256) void scatter_sorted(const float* __restrict__ boxes,
                                                      const unsigned* __restrict__ rank,
                                                      int* __restrict__ order,
                                                      float* __restrict__ sboxes,
                                                      float* __restrict__ sareas) {
    int n = blockIdx.x * 256 + threadIdx.x;
    unsigned r = rank[n];
    order[r] = n;
    float4 bx = ((const float4*)boxes)[n];
    ((float4*)sboxes)[r] = bx;
    sareas[r] = (bx.z - bx.x) * (bx.w - bx.y);
}

// ---------------- candidate detection over upper-tri 256x256 tiles ----------------
__global__ __launch_bounds__(256) void cand_detect(const float* __restrict__ sboxes,
                                                   const float* __restrict__ sareas,
                                                   unsigned long long* __restrict__ rnz64) {
    __shared__ float CX1[256], CY1[256], CX2[256], CY2[256], CAR[256];
    int rem = blockIdx.x, rb = 0;
    while (rem >= 36 - rb) { rem -= 36 - rb; ++rb; }
    int s = rb + rem;
    int tid = threadIdx.x;
    int i = rb * 256 + tid;
    {
        int j = s * 256 + tid;
        float4 cb = ((const float4*)sboxes)[j];
        CX1[tid] = cb.x; CY1[tid] = cb.y; CX2[tid] = cb.z; CY2[tid] = cb.w;
        CAR[tid] = sareas[j];
    }
    __syncthreads();
    float4 b = ((const float4*)sboxes)[i];
    float ar = sareas[i];
    bool any = false;

    if (s == rb) {
        for (int idx = tid + 1; idx < 256; ++idx) {
            float ix = fminf(b.z, CX2[idx]) - fmaxf(b.x, CX1[idx]);
            float iy = fminf(b.w, CY2[idx]) - fmaxf(b.y, CY1[idx]);
            float inter = fmaxf(ix, 0.f) * fmaxf(iy, 0.f);
            float denom = ar + CAR[idx] - inter;
            if (inter > 0.85f * denom) {
                if (inter / denom > IOU_THRF) any = true;
            }
        }
    } else {
        const float4* X1v = (const float4*)CX1;
        const float4* Y1v = (const float4*)CY1;
        const float4* X2v = (const float4*)CX2;
        const float4* Y2v = (const float4*)CY2;
        const float4* ARv = (const float4*)CAR;
        #pragma unroll 2
        for (int q = 0; q < 64; ++q) {
            float4 x1 = X1v[q], y1 = Y1v[q], x2 = X2v[q], y2 = Y2v[q], aa = ARv[q];
            #define CCHK(k) { \
                float ix = fminf(b.z, x2.k) - fmaxf(b.x, x1.k); \
                float iy = fminf(b.w, y2.k) - fmaxf(b.y, y1.k); \
                float inter = fmaxf(ix, 0.f) * fmaxf(iy, 0.f);  \
                float denom = ar + aa.k - inter;                \
                if (inter > 0.85f * denom) {                    \
                    if (inter / denom > IOU_THRF) any = true;   \
                } }
            CCHK(x) CCHK(y) CCHK(z) CCHK(w)
            #undef CCHK
        }
    }
    unsigned long long bal = __ballot(any);
    if ((tid & 63) == 0) atomicOr(&rnz64[rb * 4 + (tid >> 6)], bal);
}

__device__ inline unsigned long long rdl64(unsigned long long v, int l) {
    unsigned lo = (unsigned)__builtin_amdgcn_readlane((int)(unsigned)(v & 0xffffffffull), l);
    unsigned hi = (unsigned)__builtin_amdgcn_readlane((int)(unsigned)(v >> 32), l);
    return ((unsigned long long)hi << 32) | lo;
}

// ---------------- compact candidates (order-preserving), 1 wave, registers only ----------------
__global__ __launch_bounds__(64) void compact_cand(const unsigned long long* __restrict__ rnz64,
                                                   const float* __restrict__ sboxes,
                                                   const float* __restrict__ sareas,
                                                   int* __restrict__ cidx,
                                                   float4* __restrict__ cboxes,
                                                   float* __restrict__ carea,
                                                   int* __restrict__ knum) {
    int lane = threadIdx.x;
    unsigned long long rz0 = rnz64[lane];
    unsigned long long rz1 = rnz64[64 + lane];
    unsigned long long rz2 = rnz64[128 + lane];
    int base = 0;
    for (int w = 0; w < NWORDS; ++w) {
        unsigned long long bits = (w < 64) ? rdl64(rz0, w)
                                : (w < 128) ? rdl64(rz1, w - 64) : rdl64(rz2, w - 128);
        if (bits & (1ull << lane)) {
            int pos = base + (int)__popcll(bits & ((1ull << lane) - 1ull));
            if (pos < CAND_CAP) {
                int i = w * 64 + lane;
                cidx[pos] = i;
                cboxes[pos] = ((const float4*)sboxes)[i];
                carea[pos] = sareas[i];
            }
        }
        base += (int)__popcll(bits);
    }
    if (lane == 0) knum[0] = base < CAND_CAP ? base : CAND_CAP;
}

// ---------------- candidate x candidate gating matrix ----------------
// gate[a*64 + w] bit t = candidate a suppresses candidate w*64+t (ordinal >, IOU>thr)
__global__ __launch_bounds__(256) void gate_build(const float4* __restrict__ cboxes,
                                                  const float* __restrict__ carea,
                                                  const int* __restrict__ knum,
                                                  unsigned long long* __restrict__ gate) {
    int Kc = knum[0];
    int a = blockIdx.x * 4 + (threadIdx.x >> 6);
    int w = threadIdx.x & 63;
    if (a >= Kc) return;
    float4 b = cboxes[a];
    float ar = carea[a];
    unsigned long long bits = 0ull;
    int cbase = w * 64;
    if (cbase < Kc) {
        int lim = Kc - cbase; if (lim > 64) lim = 64;
        for (int t = 0; t < lim; ++t) {
            int c = cbase + t;
            if (c > a) {
                float4 cb = cboxes[c];
                float ix = fminf(b.z, cb.z) - fmaxf(b.x, cb.x);
                float iy = fminf(b.w, cb.w) - fmaxf(b.y, cb.y);
                float inter = fmaxf(ix, 0.f) * fmaxf(iy, 0.f);
                float denom = ar + carea[c] - inter;
                if (inter > 0.85f * denom) {
                    if (inter / denom > IOU_THRF) bits |= (1ull << t);
                }
            }
        }
    }
    gate[(size_t)a * 64 + w] = bits;
}

// ---------------- serial greedy scan: LDS-staged word blocks ----------------
// Per word w: stage the 64-row x 64-word gate block into LDS (coalesced),
// then resolve fires against LDS (~120cy) instead of HBM/L2 (~600-900cy).
// sup is lane-distributed (lane l owns candidate word l), OR'd immediately.
__global__ __launch_bounds__(64) void nms_scan3(const unsigned long long* __restrict__ gate,
                                                const int* __restrict__ knum,
                                                int* __restrict__ fire_ord,
                                                int* __restrict__ fire_cnt) {
    __shared__ unsigned long long tile[64][64];   // 32 KB
    int lane = threadIdx.x;
    int Kc = knum[0];
    int nw = (Kc + 63) >> 6;
    unsigned long long sup = 0ull;
    int nf = 0;
    int half = lane >> 5;                // 0/1: row parity within pair
    int cpair = (lane & 31) * 2;         // column u64 pair 0,2,..,62

    for (int w = 0; w < nw; ++w) {
        // ---- stage block w: rows w*64..w*64+63, cols 0..63 (1KB per load instr)
        const unsigned long long* gp = gate + ((size_t)(w * 64 + half) * 64 + cpair);
        #pragma unroll 8
        for (int rr = 0; rr < 32; ++rr) {
            ulonglong2 v = *(const ulonglong2*)(gp + (size_t)2 * rr * 64);
            *(ulonglong2*)&tile[2 * rr + half][cpair] = v;
        }
        __syncthreads();

        int rem = Kc - (w << 6);
        unsigned long long maskw = (rem >= 64) ? ~0ull : ((1ull << rem) - 1ull);
        unsigned long long alive = ~rdl64(sup, w) & maskw;
        while (alive) {
            int t = __builtin_ctzll(alive);
            if (lane == 0 && nf < FIRE_CAP) fire_ord[nf] = (w << 6) + t;
            ++nf;
            unsigned long long g = tile[t][lane];   // LDS, lane-distributed row
            sup |= g;
            alive &= ~(1ull << t);
            alive &= ~rdl64(g, w);
        }
        __syncthreads();   // all lanes done reading tile before next overwrite
    }
    if (lane == 0) fire_cnt[0] = nf < FIRE_CAP ? nf : FIRE_CAP;
}

// ---------------- finalize: recompute suppression vs fires, write output ----------------
__global__ __launch_bounds__(256) void finalize(const float* __restrict__ sboxes,
                                                const float* __restrict__ sareas,
                                                const float* __restrict__ scores,
                                                const int* __restrict__ order,
                                                const float4* __restrict__ cboxes,
                                                const float* __restrict__ carea,
                                                const int* __restrict__ cidx,
                                                const int* __restrict__ fire_ord,
                                                const int* __restrict__ fire_cnt,
                                                float* __restrict__ out) {
    __shared__ float4 FB[FIRE_CAP];
    __shared__ float FA[FIRE_CAP];
    __shared__ int FP[FIRE_CAP];
    int tid = threadIdx.x;
    int fc = fire_cnt[0];
    for (int k = tid; k < fc; k += 256) {
        int o = fire_ord[k];
        FB[k] = cboxes[o];
        FA[k] = carea[o];
        FP[k] = cidx[o];
    }
    __syncthreads();
    int j = blockIdx.x * 256 + tid;   // sorted index
    float4 b = ((const float4*)sboxes)[j];
    float aj = sareas[j];
    bool supp = false;
    for (int k = 0; k < fc; ++k) {
        float4 f = FB[k];
        float ix = fminf(b.z, f.z) - fmaxf(b.x, f.x);
        float iy = fminf(b.w, f.w) - fmaxf(b.y, f.y);
        float inter = fmaxf(ix, 0.f) * fmaxf(iy, 0.f);
        float denom = FA[k] + aj - inter;
        if (FP[k] < j && inter > 0.85f * denom) {
            if (inter / denom > IOU_THRF) supp = true;
        }
    }
    int n = order[j];
    float m = supp ? 0.f : 1.f;
    out[(size_t)n * 5 + 0] = b.x * m;
    out[(size_t)n * 5 + 1] = b.y * m;
    out[(size_t)n * 5 + 2] = b.z * m;
    out[(size_t)n * 5 + 3] = b.w * m;
    out[(size_t)n * 5 + 4] = scores[n] * m;
}

extern "C" void kernel_launch(void* const* d_in, const int* in_sizes, int n_in,
                              void* d_out, int out_size, void* d_ws, size_t ws_size,
                              hipStream_t stream) {
    const float* x      = (const float*)d_in[0];
    const float* anchors= (const float*)d_in[1];
    const float* dw_w   = (const float*)d_in[2];
    const float* pw_w   = (const float*)d_in[3];
    const float* bn1g   = (const float*)d_in[4];
    const float* bn1b   = (const float*)d_in[5];
    const float* bn1m   = (const float*)d_in[6];
    const float* bn1v   = (const float*)d_in[7];
    const float* anc_w  = (const float*)d_in[8];
    const float* ag     = (const float*)d_in[9];
    const float* ab     = (const float*)d_in[10];
    const float* am     = (const float*)d_in[11];
    const float* av     = (const float*)d_in[12];
    const float* obj_w  = (const float*)d_in[13];
    const float* og     = (const float*)d_in[14];
    const float* ob     = (const float*)d_in[15];
    const float* om     = (const float*)d_in[16];
    const float* ov     = (const float*)d_in[17];
    float* out = (float*)d_out;

    char* ws = (char*)d_ws;
    size_t off = 0;
    auto alloc = [&](size_t bytes) -> char* {
        char* p = ws + off;
        off = (off + bytes + 255) & ~(size_t)255;
        return p;
    };
    float* h0      = (float*)alloc(256 * 1024 * 4);
    float* h1      = (float*)alloc(256 * 1024 * 4);
    float* boxes   = (float*)alloc(NBOX * 4 * 4);
    float* scores  = (float*)alloc(NBOX * 4);
    unsigned* rank = (unsigned*)alloc(NBOX * 4);
    int* order     = (int*)alloc(NBOX * 4);
    float* sboxes  = (float*)alloc(NBOX * 4 * 4);
    float* sareas  = (float*)alloc(NBOX * 4);
    unsigned long long* rnz64 = (unsigned long long*)alloc(192 * 8);
    int* cidx      = (int*)alloc(CAND_CAP * 4);
    float4* cboxes = (float4*)alloc(CAND_CAP * 16);
    float* carea   = (float*)alloc(CAND_CAP * 4);
    int* knum      = (int*)alloc(256);
    int* fire_ord  = (int*)alloc(FIRE_CAP * 4);
    int* fire_cnt  = (int*)alloc(256);
    unsigned long long* gate = (unsigned long long*)alloc((size_t)CAND_CAP * 64 * 8);

    hipMemsetAsync(rank, 0, NBOX * 4, stream);
    hipMemsetAsync(rnz64, 0, 192 * 8, stream);

    dw_conv<<<1024, 256, 0, stream>>>(x, dw_w, h0);
    pw_conv<<<dim3(4, 64), 256, 0, stream>>>(h0, pw_w, bn1g, bn1b, bn1m, bn1v, h1);
    heads<<<dim3(4, 45), 256, 0, stream>>>(h1, anc_w, ag, ab, am, av,
                                           obj_w, og, ob, om, ov, anchors, boxes, scores);
    rank_partial<<<dim3(36, 16), 256, 0, stream>>>(scores, rank);
    scatter_sorted<<<36, 256, 0, stream>>>(boxes, rank, order, sboxes, sareas);
    cand_detect<<<NTILES, 256, 0, stream>>>(sboxes, sareas, rnz64);
    compact_cand<<<1, 64, 0, stream>>>(rnz64, sboxes, sareas, cidx, cboxes, carea, knum);
    gate_build<<<CAND_CAP / 4, 256, 0, stream>>>(cboxes, carea, knum, gate);
    nms_scan3<<<1, 64, 0, stream>>>(gate, knum, fire_ord, fire_cnt);
    finalize<<<36, 256, 0, stream>>>(sboxes, sareas, scores, order,
                                     cboxes, carea, cidx, fire_ord, fire_cnt, out);
}

// Round 10
// 369.327 us; speedup vs baseline: 1.2069x; 1.1715x over previous
//
#include <hip/hip_runtime.h>
#include <hip/hip_bf16.h>

#define EPSF 1e-5f
#define IOU_THRF 0.9f
#define NBOX 9216
#define NWORDS 144   // 9216/64
#define CAND_CAP 4096
#define FIRE_CAP 1024
#define NTILES 666   // 36*37/2 upper-tri 256x256 tiles

// ---------------- depthwise 3x3 conv, C=256, 32x32, pad 1 ----------------
__global__ __launch_bounds__(256) void dw_conv(const float* __restrict__ x,
                                               const float* __restrict__ w,
                                               float* __restrict__ h0) {
    int idx = blockIdx.x * 256 + threadIdx.x;   // 262144 threads
    int c = idx >> 10, p = idx & 1023;
    int yy = p >> 5, xx = p & 31;
    const float* xi = x + (c << 10);
    const float* wc = w + c * 9;
    float acc = 0.f;
    #pragma unroll
    for (int dy = -1; dy <= 1; ++dy) {
        int y2 = yy + dy;
        if ((unsigned)y2 >= 32u) continue;
        #pragma unroll
        for (int dx = -1; dx <= 1; ++dx) {
            int x2 = xx + dx;
            if ((unsigned)x2 >= 32u) continue;
            acc += wc[(dy + 1) * 3 + (dx + 1)] * xi[y2 * 32 + x2];
        }
    }
    h0[idx] = acc;
}

// ---------------- pointwise 256x256 GEMM + BN1 + leaky relu ----------------
__global__ __launch_bounds__(256) void pw_conv(const float* __restrict__ h0,
                                               const float* __restrict__ w,
                                               const float* __restrict__ g,
                                               const float* __restrict__ b,
                                               const float* __restrict__ mu,
                                               const float* __restrict__ var,
                                               float* __restrict__ h1) {
    int p = blockIdx.x * 256 + threadIdx.x;
    int o0 = blockIdx.y * 4;
    float acc0 = 0.f, acc1 = 0.f, acc2 = 0.f, acc3 = 0.f;
    for (int c = 0; c < 256; ++c) {
        float hv = h0[(c << 10) + p];
        acc0 += w[(o0 + 0) * 256 + c] * hv;
        acc1 += w[(o0 + 1) * 256 + c] * hv;
        acc2 += w[(o0 + 2) * 256 + c] * hv;
        acc3 += w[(o0 + 3) * 256 + c] * hv;
    }
    float accs[4] = {acc0, acc1, acc2, acc3};
    #pragma unroll
    for (int k = 0; k < 4; ++k) {
        int o = o0 + k;
        float inv = 1.0f / sqrtf(var[o] + EPSF);
        float v = (accs[k] - mu[o]) * (inv * g[o]) + b[o];
        v = (v >= 0.f) ? v : 0.01f * v;
        h1[(o << 10) + p] = v;
    }
}

// ---------------- heads: anc (36 ch) + obj (9 ch) GEMV + BN + decode ----------------
__global__ __launch_bounds__(256) void heads(const float* __restrict__ h1,
                                             const float* __restrict__ anc_w,
                                             const float* __restrict__ ag,
                                             const float* __restrict__ ab,
                                             const float* __restrict__ am,
                                             const float* __restrict__ av,
                                             const float* __restrict__ obj_w,
                                             const float* __restrict__ og,
                                             const float* __restrict__ ob,
                                             const float* __restrict__ om,
                                             const float* __restrict__ ov,
                                             const float* __restrict__ anchors,
                                             float* __restrict__ boxes,
                                             float* __restrict__ scores) {
    int p = blockIdx.x * 256 + threadIdx.x;
    int o = blockIdx.y;
    const float* wrow = (o < 36) ? (anc_w + o * 256) : (obj_w + (o - 36) * 256);
    float acc = 0.f;
    for (int c = 0; c < 256; ++c) acc += wrow[c] * h1[(c << 10) + p];
    if (o < 36) {
        float inv = 1.0f / sqrtf(av[o] + EPSF);
        float v = (acc - am[o]) * (inv * ag[o]) + ab[o];
        v = fminf(fmaxf(v, 0.f), 6.f);           // clip 0..6
        int a = o >> 2, k = o & 3;
        float anch = anchors[a * 4 + k];
        float val = (k < 2) ? (v + anch) : (expf(v) * anch);
        boxes[(size_t)(a * 1024 + p) * 4 + k] = val;
    } else {
        int a = o - 36;
        float inv = 1.0f / sqrtf(ov[a] + EPSF);
        float v = (acc - om[a]) * (inv * og[a]) + ob[a];
        scores[a * 1024 + p] = 1.0f / (1.0f + expf(-v));
    }
}

// ---------------- rank = stable-descending-argsort position, O(N^2) count ----------------
// grid (36 n-blocks, 16 m-chunks of 576), 256 thr
__global__ __launch_bounds__(256) void rank_partial(const float* __restrict__ scores,
                                                    unsigned* __restrict__ rank) {
    __shared__ float4 sm[144];
    int mbase = blockIdx.y * 576;
    for (int t = threadIdx.x; t < 144; t += 256)
        sm[t] = ((const float4*)(scores + mbase))[t];
    __syncthreads();
    int n = blockIdx.x * 256 + threadIdx.x;
    float s = scores[n];
    unsigned cnt = 0;
    for (int q = 0; q < 144; ++q) {
        float4 v = sm[q];
        int m = mbase + q * 4;
        cnt += (v.x > s) || (v.x == s && (m + 0) < n);
        cnt += (v.y > s) || (v.y == s && (m + 1) < n);
        cnt += (v.z > s) || (v.z == s && (m + 2) < n);
        cnt += (v.w > s) || (v.w == s && (m + 3) < n);
    }
    atomicAdd(&rank[n], cnt);
}

// ---------------- scatter into sorted order ----------------
__global__ __launch_bounds__(256) void scatter_sorted(const float* __restrict__ boxes,
                                                      const unsigned* __restrict__ rank,
                                                      int* __restrict__ order,
                                                      float* __restrict__ sboxes,
                                                      float* __restrict__ sareas) {
    int n = blockIdx.x * 256 + threadIdx.x;
    unsigned r = rank[n];
    order[r] = n;
    float4 bx = ((const float4*)boxes)[n];
    ((float4*)sboxes)[r] = bx;
    sareas[r] = (bx.z - bx.x) * (bx.w - bx.y);
}

// ---------------- candidate detection over upper-tri 256x256 tiles ----------------
__global__ __launch_bounds__(256) void cand_detect(const float* __restrict__ sboxes,
                                                   const float* __restrict__ sareas,
                                                   unsigned long long* __restrict__ rnz64) {
    __shared__ float CX1[256], CY1[256], CX2[256], CY2[256], CAR[256];
    int rem = blockIdx.x, rb = 0;
    while (rem >= 36 - rb) { rem -= 36 - rb; ++rb; }
    int s = rb + rem;
    int tid = threadIdx.x;
    int i = rb * 256 + tid;
    {
        int j = s * 256 + tid;
        float4 cb = ((const float4*)sboxes)[j];
        CX1[tid] = cb.x; CY1[tid] = cb.y; CX2[tid] = cb.z; CY2[tid] = cb.w;
        CAR[tid] = sareas[j];
    }
    __syncthreads();
    float4 b = ((const float4*)sboxes)[i];
    float ar = sareas[i];
    bool any = false;

    if (s == rb) {
        for (int idx = tid + 1; idx < 256; ++idx) {
            float ix = fminf(b.z, CX2[idx]) - fmaxf(b.x, CX1[idx]);
            float iy = fminf(b.w, CY2[idx]) - fmaxf(b.y, CY1[idx]);
            float inter = fmaxf(ix, 0.f) * fmaxf(iy, 0.f);
            float denom = ar + CAR[idx] - inter;
            if (inter > 0.85f * denom) {
                if (inter / denom > IOU_THRF) any = true;
            }
        }
    } else {
        const float4* X1v = (const float4*)CX1;
        const float4* Y1v = (const float4*)CY1;
        const float4* X2v = (const float4*)CX2;
        const float4* Y2v = (const float4*)CY2;
        const float4* ARv = (const float4*)CAR;
        #pragma unroll 2
        for (int q = 0; q < 64; ++q) {
            float4 x1 = X1v[q], y1 = Y1v[q], x2 = X2v[q], y2 = Y2v[q], aa = ARv[q];
            #define CCHK(k) { \
                float ix = fminf(b.z, x2.k) - fmaxf(b.x, x1.k); \
                float iy = fminf(b.w, y2.k) - fmaxf(b.y, y1.k); \
                float inter = fmaxf(ix, 0.f) * fmaxf(iy, 0.f);  \
                float denom = ar + aa.k - inter;                \
                if (inter > 0.85f * denom) {                    \
                    if (inter / denom > IOU_THRF) any = true;   \
                } }
            CCHK(x) CCHK(y) CCHK(z) CCHK(w)
            #undef CCHK
        }
    }
    unsigned long long bal = __ballot(any);
    if ((tid & 63) == 0) atomicOr(&rnz64[rb * 4 + (tid >> 6)], bal);
}

__device__ inline unsigned long long rdl64(unsigned long long v, int l) {
    unsigned lo = (unsigned)__builtin_amdgcn_readlane((int)(unsigned)(v & 0xffffffffull), l);
    unsigned hi = (unsigned)__builtin_amdgcn_readlane((int)(unsigned)(v >> 32), l);
    return ((unsigned long long)hi << 32) | lo;
}

// ---------------- compact candidates (order-preserving), 1 wave, registers only ----------------
__global__ __launch_bounds__(64) void compact_cand(const unsigned long long* __restrict__ rnz64,
                                                   const float* __restrict__ sboxes,
                                                   const float* __restrict__ sareas,
                                                   int* __restrict__ cidx,
                                                   float4* __restrict__ cboxes,
                                                   float* __restrict__ carea,
                                                   int* __restrict__ knum) {
    int lane = threadIdx.x;
    unsigned long long rz0 = rnz64[lane];
    unsigned long long rz1 = rnz64[64 + lane];
    unsigned long long rz2 = rnz64[128 + lane];
    int base = 0;
    for (int w = 0; w < NWORDS; ++w) {
        unsigned long long bits = (w < 64) ? rdl64(rz0, w)
                                : (w < 128) ? rdl64(rz1, w - 64) : rdl64(rz2, w - 128);
        if (bits & (1ull << lane)) {
            int pos = base + (int)__popcll(bits & ((1ull << lane) - 1ull));
            if (pos < CAND_CAP) {
                int i = w * 64 + lane;
                cidx[pos] = i;
                cboxes[pos] = ((const float4*)sboxes)[i];
                carea[pos] = sareas[i];
            }
        }
        base += (int)__popcll(bits);
    }
    if (lane == 0) knum[0] = base < CAND_CAP ? base : CAND_CAP;
}

// ---------------- candidate x candidate gating matrix ----------------
// gate[a*64 + w] bit t = candidate a suppresses candidate w*64+t (ordinal >, IOU>thr)
__global__ __launch_bounds__(256) void gate_build(const float4* __restrict__ cboxes,
                                                  const float* __restrict__ carea,
                                                  const int* __restrict__ knum,
                                                  unsigned long long* __restrict__ gate) {
    int Kc = knum[0];
    int a = blockIdx.x * 4 + (threadIdx.x >> 6);
    int w = threadIdx.x & 63;
    if (a >= Kc) return;
    float4 b = cboxes[a];
    float ar = carea[a];
    unsigned long long bits = 0ull;
    int cbase = w * 64;
    if (cbase < Kc) {
        int lim = Kc - cbase; if (lim > 64) lim = 64;
        for (int t = 0; t < lim; ++t) {
            int c = cbase + t;
            if (c > a) {
                float4 cb = cboxes[c];
                float ix = fminf(b.z, cb.z) - fmaxf(b.x, cb.x);
                float iy = fminf(b.w, cb.w) - fmaxf(b.y, cb.y);
                float inter = fmaxf(ix, 0.f) * fmaxf(iy, 0.f);
                float denom = ar + carea[c] - inter;
                if (inter > 0.85f * denom) {
                    if (inter / denom > IOU_THRF) bits |= (1ull << t);
                }
            }
        }
    }
    gate[(size_t)a * 64 + w] = bits;
}

// ---------------- serial greedy scan: 8-wave pipelined LDS staging ----------------
// All 8 waves cooperatively stage gate block w+1 (32KB, coalesced, one latency
// period) into the double buffer while wave 0 resolves block w from LDS.
__global__ __launch_bounds__(512) void nms_scan4(const unsigned long long* __restrict__ gate,
                                                 const int* __restrict__ knum,
                                                 int* __restrict__ fire_ord,
                                                 int* __restrict__ fire_cnt) {
    __shared__ unsigned long long tile[2][4096];   // 64 KB double buffer
    int tid = threadIdx.x;
    int lane = tid & 63;
    int Kc = knum[0];
    int nw = (Kc + 63) >> 6;

    // prologue: stage block 0
    {
        const ulonglong2* src = (const ulonglong2*)gate;
        ulonglong2* dst = (ulonglong2*)tile[0];
        #pragma unroll
        for (int q = 0; q < 4; ++q) dst[tid + 512 * q] = src[tid + 512 * q];
    }
    __syncthreads();

    unsigned long long sup = 0ull;   // wave0: lane l owns candidate word l
    int nf = 0;

    for (int w = 0; w < nw; ++w) {
        int cur = w & 1, nxt = cur ^ 1;
        // all waves: stage block w+1 (overlaps with wave0's resolve below)
        if (w + 1 < nw) {
            const ulonglong2* src = (const ulonglong2*)(gate + (size_t)(w + 1) * 4096);
            ulonglong2* dst = (ulonglong2*)tile[nxt];
            #pragma unroll
            for (int q = 0; q < 4; ++q) dst[tid + 512 * q] = src[tid + 512 * q];
        }
        // wave 0: resolve block w from LDS
        if (tid < 64) {
            int rem = Kc - (w << 6);
            unsigned long long maskw = (rem >= 64) ? ~0ull : ((1ull << rem) - 1ull);
            unsigned long long alive = ~rdl64(sup, w) & maskw;
            while (alive) {
                int t = __builtin_ctzll(alive);
                if (lane == 0 && nf < FIRE_CAP) fire_ord[nf] = (w << 6) + t;
                ++nf;
                unsigned long long g = tile[cur][t * 64 + lane];
                sup |= g;
                alive &= ~(1ull << t);
                alive &= ~rdl64(g, w);
            }
        }
        __syncthreads();
    }
    if (tid == 0) fire_cnt[0] = nf < FIRE_CAP ? nf : FIRE_CAP;
}

// ---------------- finalize: recompute suppression vs fires, write output ----------------
__global__ __launch_bounds__(256) void finalize(const float* __restrict__ sboxes,
                                                const float* __restrict__ sareas,
                                                const float* __restrict__ scores,
                                                const int* __restrict__ order,
                                                const float4* __restrict__ cboxes,
                                                const float* __restrict__ carea,
                                                const int* __restrict__ cidx,
                                                const int* __restrict__ fire_ord,
                                                const int* __restrict__ fire_cnt,
                                                float* __restrict__ out) {
    __shared__ float4 FB[FIRE_CAP];
    __shared__ float FA[FIRE_CAP];
    __shared__ int FP[FIRE_CAP];
    int tid = threadIdx.x;
    int fc = fire_cnt[0];
    for (int k = tid; k < fc; k += 256) {
        int o = fire_ord[k];
        FB[k] = cboxes[o];
        FA[k] = carea[o];
        FP[k] = cidx[o];
    }
    __syncthreads();
    int j = blockIdx.x * 256 + tid;   // sorted index
    float4 b = ((const float4*)sboxes)[j];
    float aj = sareas[j];
    bool supp = false;
    for (int k = 0; k < fc; ++k) {
        float4 f = FB[k];
        float ix = fminf(b.z, f.z) - fmaxf(b.x, f.x);
        float iy = fminf(b.w, f.w) - fmaxf(b.y, f.y);
        float inter = fmaxf(ix, 0.f) * fmaxf(iy, 0.f);
        float denom = FA[k] + aj - inter;
        if (FP[k] < j && inter > 0.85f * denom) {
            if (inter / denom > IOU_THRF) supp = true;
        }
    }
    int n = order[j];
    float m = supp ? 0.f : 1.f;
    out[(size_t)n * 5 + 0] = b.x * m;
    out[(size_t)n * 5 + 1] = b.y * m;
    out[(size_t)n * 5 + 2] = b.z * m;
    out[(size_t)n * 5 + 3] = b.w * m;
    out[(size_t)n * 5 + 4] = scores[n] * m;
}

extern "C" void kernel_launch(void* const* d_in, const int* in_sizes, int n_in,
                              void* d_out, int out_size, void* d_ws, size_t ws_size,
                              hipStream_t stream) {
    const float* x      = (const float*)d_in[0];
    const float* anchors= (const float*)d_in[1];
    const float* dw_w   = (const float*)d_in[2];
    const float* pw_w   = (const float*)d_in[3];
    const float* bn1g   = (const float*)d_in[4];
    const float* bn1b   = (const float*)d_in[5];
    const float* bn1m   = (const float*)d_in[6];
    const float* bn1v   = (const float*)d_in[7];
    const float* anc_w  = (const float*)d_in[8];
    const float* ag     = (const float*)d_in[9];
    const float* ab     = (const float*)d_in[10];
    const float* am     = (const float*)d_in[11];
    const float* av     = (const float*)d_in[12];
    const float* obj_w  = (const float*)d_in[13];
    const float* og     = (const float*)d_in[14];
    const float* ob     = (const float*)d_in[15];
    const float* om     = (const float*)d_in[16];
    const float* ov     = (const float*)d_in[17];
    float* out = (float*)d_out;

    char* ws = (char*)d_ws;
    size_t off = 0;
    auto alloc = [&](size_t bytes) -> char* {
        char* p = ws + off;
        off = (off + bytes + 255) & ~(size_t)255;
        return p;
    };
    float* h0      = (float*)alloc(256 * 1024 * 4);
    float* h1      = (float*)alloc(256 * 1024 * 4);
    float* boxes   = (float*)alloc(NBOX * 4 * 4);
    float* scores  = (float*)alloc(NBOX * 4);
    unsigned* rank = (unsigned*)alloc(NBOX * 4);
    int* order     = (int*)alloc(NBOX * 4);
    float* sboxes  = (float*)alloc(NBOX * 4 * 4);
    float* sareas  = (float*)alloc(NBOX * 4);
    unsigned long long* rnz64 = (unsigned long long*)alloc(192 * 8);
    int* cidx      = (int*)alloc(CAND_CAP * 4);
    float4* cboxes = (float4*)alloc(CAND_CAP * 16);
    float* carea   = (float*)alloc(CAND_CAP * 4);
    int* knum      = (int*)alloc(256);
    int* fire_ord  = (int*)alloc(FIRE_CAP * 4);
    int* fire_cnt  = (int*)alloc(256);
    unsigned long long* gate = (unsigned long long*)alloc((size_t)CAND_CAP * 64 * 8);

    hipMemsetAsync(rank, 0, NBOX * 4, stream);
    hipMemsetAsync(rnz64, 0, 192 * 8, stream);

    dw_conv<<<1024, 256, 0, stream>>>(x, dw_w, h0);
    pw_conv<<<dim3(4, 64), 256, 0, stream>>>(h0, pw_w, bn1g, bn1b, bn1m, bn1v, h1);
    heads<<<dim3(4, 45), 256, 0, stream>>>(h1, anc_w, ag, ab, am, av,
                                           obj_w, og, ob, om, ov, anchors, boxes, scores);
    rank_partial<<<dim3(36, 16), 256, 0, stream>>>(scores, rank);
    scatter_sorted<<<36, 256, 0, stream>>>(boxes, rank, order, sboxes, sareas);
    cand_detect<<<NTILES, 256, 0, stream>>>(sboxes, sareas, rnz64);
    compact_cand<<<1, 64, 0, stream>>>(rnz64, sboxes, sareas, cidx, cboxes, carea, knum);
    gate_build<<<CAND_CAP / 4, 256, 0, stream>>>(cboxes, carea, knum, gate);
    nms_scan4<<<1, 512, 0, stream>>>(gate, knum, fire_ord, fire_cnt);
    finalize<<<36, 256, 0, stream>>>(sboxes, sareas, scores, order,
                                     cboxes, carea, cidx, fire_ord, fire_cnt, out);
}

// Round 11
// 349.759 us; speedup vs baseline: 1.2744x; 1.0559x over previous
//
#include <hip/hip_runtime.h>
#include <hip/hip_bf16.h>

#define EPSF 1e-5f
#define IOU_THRF 0.9f
#define NBOX 9216
#define NWORDS 144   // 9216/64
#define CAND_CAP 4096
#define FIRE_CAP 1024
#define NTILES 666   // 36*37/2 upper-tri 256x256 tiles

// ---------------- depthwise 3x3 conv, C=256, 32x32, pad 1 ----------------
__global__ __launch_bounds__(256) void dw_conv(const float* __restrict__ x,
                                               const float* __restrict__ w,
                                               float* __restrict__ h0) {
    int idx = blockIdx.x * 256 + threadIdx.x;   // 262144 threads
    int c = idx >> 10, p = idx & 1023;
    int yy = p >> 5, xx = p & 31;
    const float* xi = x + (c << 10);
    const float* wc = w + c * 9;
    float acc = 0.f;
    #pragma unroll
    for (int dy = -1; dy <= 1; ++dy) {
        int y2 = yy + dy;
        if ((unsigned)y2 >= 32u) continue;
        #pragma unroll
        for (int dx = -1; dx <= 1; ++dx) {
            int x2 = xx + dx;
            if ((unsigned)x2 >= 32u) continue;
            acc += wc[(dy + 1) * 3 + (dx + 1)] * xi[y2 * 32 + x2];
        }
    }
    h0[idx] = acc;
}

// ---------------- pointwise 256x256 GEMM + BN1 + leaky relu ----------------
__global__ __launch_bounds__(256) void pw_conv(const float* __restrict__ h0,
                                               const float* __restrict__ w,
                                               const float* __restrict__ g,
                                               const float* __restrict__ b,
                                               const float* __restrict__ mu,
                                               const float* __restrict__ var,
                                               float* __restrict__ h1) {
    int p = blockIdx.x * 256 + threadIdx.x;
    int o0 = blockIdx.y * 4;
    float acc0 = 0.f, acc1 = 0.f, acc2 = 0.f, acc3 = 0.f;
    for (int c = 0; c < 256; ++c) {
        float hv = h0[(c << 10) + p];
        acc0 += w[(o0 + 0) * 256 + c] * hv;
        acc1 += w[(o0 + 1) * 256 + c] * hv;
        acc2 += w[(o0 + 2) * 256 + c] * hv;
        acc3 += w[(o0 + 3) * 256 + c] * hv;
    }
    float accs[4] = {acc0, acc1, acc2, acc3};
    #pragma unroll
    for (int k = 0; k < 4; ++k) {
        int o = o0 + k;
        float inv = 1.0f / sqrtf(var[o] + EPSF);
        float v = (accs[k] - mu[o]) * (inv * g[o]) + b[o];
        v = (v >= 0.f) ? v : 0.01f * v;
        h1[(o << 10) + p] = v;
    }
}

// ---------------- heads: anc (36 ch) + obj (9 ch) GEMV + BN + decode ----------------
__global__ __launch_bounds__(256) void heads(const float* __restrict__ h1,
                                             const float* __restrict__ anc_w,
                                             const float* __restrict__ ag,
                                             const float* __restrict__ ab,
                                             const float* __restrict__ am,
                                             const float* __restrict__ av,
                                             const float* __restrict__ obj_w,
                                             const float* __restrict__ og,
                                             const float* __restrict__ ob,
                                             const float* __restrict__ om,
                                             const float* __restrict__ ov,
                                             const float* __restrict__ anchors,
                                             float* __restrict__ boxes,
                                             float* __restrict__ scores) {
    int p = blockIdx.x * 256 + threadIdx.x;
    int o = blockIdx.y;
    const float* wrow = (o < 36) ? (anc_w + o * 256) : (obj_w + (o - 36) * 256);
    float acc = 0.f;
    for (int c = 0; c < 256; ++c) acc += wrow[c] * h1[(c << 10) + p];
    if (o < 36) {
        float inv = 1.0f / sqrtf(av[o] + EPSF);
        float v = (acc - am[o]) * (inv * ag[o]) + ab[o];
        v = fminf(fmaxf(v, 0.f), 6.f);           // clip 0..6
        int a = o >> 2, k = o & 3;
        float anch = anchors[a * 4 + k];
        float val = (k < 2) ? (v + anch) : (expf(v) * anch);
        boxes[(size_t)(a * 1024 + p) * 4 + k] = val;
    } else {
        int a = o - 36;
        float inv = 1.0f / sqrtf(ov[a] + EPSF);
        float v = (acc - om[a]) * (inv * og[a]) + ob[a];
        scores[a * 1024 + p] = 1.0f / (1.0f + expf(-v));
    }
}

// ---------------- rank = stable-descending-argsort position, O(N^2) count ----------------
// grid (36 n-blocks, 16 m-chunks of 576), 256 thr
__global__ __launch_bounds__(256) void rank_partial(const float* __restrict__ scores,
                                                    unsigned* __restrict__ rank) {
    __shared__ float4 sm[144];
    int mbase = blockIdx.y * 576;
    for (int t = threadIdx.x; t < 144; t += 256)
        sm[t] = ((const float4*)(scores + mbase))[t];
    __syncthreads();
    int n = blockIdx.x * 256 + threadIdx.x;
    float s = scores[n];
    unsigned cnt = 0;
    for (int q = 0; q < 144; ++q) {
        float4 v = sm[q];
        int m = mbase + q * 4;
        cnt += (v.x > s) || (v.x == s && (m + 0) < n);
        cnt += (v.y > s) || (v.y == s && (m + 1) < n);
        cnt += (v.z > s) || (v.z == s && (m + 2) < n);
        cnt += (v.w > s) || (v.w == s && (m + 3) < n);
    }
    atomicAdd(&rank[n], cnt);
}

// ---------------- scatter into sorted order ----------------
__global__ __launch_bounds__(256) void scatter_sorted(const float* __restrict__ boxes,
                                                      const unsigned* __restrict__ rank,
                                                      int* __restrict__ order,
                                                      float* __restrict__ sboxes,
                                                      float* __restrict__ sareas) {
    int n = blockIdx.x * 256 + threadIdx.x;
    unsigned r = rank[n];
    order[r] = n;
    float4 bx = ((const float4*)boxes)[n];
    ((float4*)sboxes)[r] = bx;
    sareas[r] = (bx.z - bx.x) * (bx.w - bx.y);
}

// ---------------- candidate detection over upper-tri 256x256 tiles ----------------
__global__ __launch_bounds__(256) void cand_detect(const float* __restrict__ sboxes,
                                                   const float* __restrict__ sareas,
                                                   unsigned long long* __restrict__ rnz64) {
    __shared__ float CX1[256], CY1[256], CX2[256], CY2[256], CAR[256];
    int rem = blockIdx.x, rb = 0;
    while (rem >= 36 - rb) { rem -= 36 - rb; ++rb; }
    int s = rb + rem;
    int tid = threadIdx.x;
    int i = rb * 256 + tid;
    {
        int j = s * 256 + tid;
        float4 cb = ((const float4*)sboxes)[j];
        CX1[tid] = cb.x; CY1[tid] = cb.y; CX2[tid] = cb.z; CY2[tid] = cb.w;
        CAR[tid] = sareas[j];
    }
    __syncthreads();
    float4 b = ((const float4*)sboxes)[i];
    float ar = sareas[i];
    bool any = false;

    if (s == rb) {
        for (int idx = tid + 1; idx < 256; ++idx) {
            float ix = fminf(b.z, CX2[idx]) - fmaxf(b.x, CX1[idx]);
            float iy = fminf(b.w, CY2[idx]) - fmaxf(b.y, CY1[idx]);
            float inter = fmaxf(ix, 0.f) * fmaxf(iy, 0.f);
            float denom = ar + CAR[idx] - inter;
            if (inter > 0.85f * denom) {
                if (inter / denom > IOU_THRF) any = true;
            }
        }
    } else {
        const float4* X1v = (const float4*)CX1;
        const float4* Y1v = (const float4*)CY1;
        const float4* X2v = (const float4*)CX2;
        const float4* Y2v = (const float4*)CY2;
        const float4* ARv = (const float4*)CAR;
        #pragma unroll 2
        for (int q = 0; q < 64; ++q) {
            float4 x1 = X1v[q], y1 = Y1v[q], x2 = X2v[q], y2 = Y2v[q], aa = ARv[q];
            #define CCHK(k) { \
                float ix = fminf(b.z, x2.k) - fmaxf(b.x, x1.k); \
                float iy = fminf(b.w, y2.k) - fmaxf(b.y, y1.k); \
                float inter = fmaxf(ix, 0.f) * fmaxf(iy, 0.f);  \
                float denom = ar + aa.k - inter;                \
                if (inter > 0.85f * denom) {                    \
                    if (inter / denom > IOU_THRF) any = true;   \
                } }
            CCHK(x) CCHK(y) CCHK(z) CCHK(w)
            #undef CCHK
        }
    }
    unsigned long long bal = __ballot(any);
    if ((tid & 63) == 0) atomicOr(&rnz64[rb * 4 + (tid >> 6)], bal);
}

__device__ inline unsigned long long rdl64(unsigned long long v, int l) {
    unsigned lo = (unsigned)__builtin_amdgcn_readlane((int)(unsigned)(v & 0xffffffffull), l);
    unsigned hi = (unsigned)__builtin_amdgcn_readlane((int)(unsigned)(v >> 32), l);
    return ((unsigned long long)hi << 32) | lo;
}

// ---------------- compact candidates (order-preserving), 1 wave ----------------
__global__ __launch_bounds__(64) void compact_cand(const unsigned long long* __restrict__ rnz64,
                                                   const float* __restrict__ sboxes,
                                                   const float* __restrict__ sareas,
                                                   int* __restrict__ cidx,
                                                   float4* __restrict__ cboxes,
                                                   float* __restrict__ carea,
                                                   int* __restrict__ knum) {
    int lane = threadIdx.x;
    unsigned long long rz0 = rnz64[lane];
    unsigned long long rz1 = rnz64[64 + lane];
    unsigned long long rz2 = rnz64[128 + lane];
    int base = 0;
    for (int w = 0; w < NWORDS; ++w) {
        unsigned long long bits = (w < 64) ? rdl64(rz0, w)
                                : (w < 128) ? rdl64(rz1, w - 64) : rdl64(rz2, w - 128);
        if (bits & (1ull << lane)) {
            int pos = base + (int)__popcll(bits & ((1ull << lane) - 1ull));
            if (pos < CAND_CAP) {
                int i = w * 64 + lane;
                cidx[pos] = i;
                cboxes[pos] = ((const float4*)sboxes)[i];
                carea[pos] = sareas[i];
            }
        }
        base += (int)__popcll(bits);
    }
    if (lane == 0) knum[0] = base < CAND_CAP ? base : CAND_CAP;
}

// ---------------- candidate x candidate gating matrix + diagonal strips ----------------
// gate[a*64 + w] bit t = candidate a suppresses candidate w*64+t (ordinal >, IOU>thr)
// diag0[a] = gate[a][a>>6], diag1[a] = gate[a][(a>>6)+1]
__global__ __launch_bounds__(256) void gate_build(const float4* __restrict__ cboxes,
                                                  const float* __restrict__ carea,
                                                  const int* __restrict__ knum,
                                                  unsigned long long* __restrict__ gate,
                                                  unsigned long long* __restrict__ diag0,
                                                  unsigned long long* __restrict__ diag1) {
    int Kc = knum[0];
    int a = blockIdx.x * 4 + (threadIdx.x >> 6);
    int w = threadIdx.x & 63;
    if (a >= Kc) return;
    float4 b = cboxes[a];
    float ar = carea[a];
    unsigned long long bits = 0ull;
    int cbase = w * 64;
    if (cbase < Kc) {
        int lim = Kc - cbase; if (lim > 64) lim = 64;
        for (int t = 0; t < lim; ++t) {
            int c = cbase + t;
            if (c > a) {
                float4 cb = cboxes[c];
                float ix = fminf(b.z, cb.z) - fmaxf(b.x, cb.x);
                float iy = fminf(b.w, cb.w) - fmaxf(b.y, cb.y);
                float inter = fmaxf(ix, 0.f) * fmaxf(iy, 0.f);
                float denom = ar + carea[c] - inter;
                if (inter > 0.85f * denom) {
                    if (inter / denom > IOU_THRF) bits |= (1ull << t);
                }
            }
        }
    }
    gate[(size_t)a * 64 + w] = bits;
    int aw = a >> 6;
    if (w == aw) diag0[a] = bits;
    if (w == aw + 1) diag1[a] = bits;
}

// ---------------- serial greedy scan: LDS strips, lazy full-row OR ----------------
// Wave 0 resolves word w using ONLY LDS (d0 within-word, d1 carry to w+1).
// Waves 1-7 concurrently load the PREVIOUS word's fire rows (global, ~512B each)
// and atomicOr them into LDS supL — needed first at word w+1 -> latency hidden.
__global__ __launch_bounds__(512) void nms_scan5(const unsigned long long* __restrict__ gate,
                                                 const unsigned long long* __restrict__ diag0,
                                                 const unsigned long long* __restrict__ diag1,
                                                 const int* __restrict__ knum,
                                                 int* __restrict__ fire_ord,
                                                 int* __restrict__ fire_cnt) {
    __shared__ unsigned long long d0L[CAND_CAP];   // 32 KB
    __shared__ unsigned long long d1L[CAND_CAP];   // 32 KB
    __shared__ unsigned long long supL[64];
    __shared__ int flist[2][64];
    __shared__ int fcnt[2];
    int tid = threadIdx.x;
    int Kc = knum[0];
    int nw = (Kc + 63) >> 6;

    // preload strips (coalesced), init sup
    #pragma unroll
    for (int q = 0; q < CAND_CAP / 512; ++q) {
        d0L[tid + 512 * q] = diag0[tid + 512 * q];
        d1L[tid + 512 * q] = diag1[tid + 512 * q];
    }
    if (tid < 64) supL[tid] = 0ull;
    if (tid == 0) { fcnt[0] = 0; fcnt[1] = 0; }
    __syncthreads();

    int nf = 0;                       // wave0-uniform
    unsigned long long carry = 0ull;  // wave0-uniform

    for (int w = 0; w < nw; ++w) {
        if (tid >= 64) {
            // waves 1-7: OR previous word's fire rows into supL
            int wv = (tid >> 6) - 1;        // 0..6
            int j = tid & 63;               // gate-row word index
            int fp = fcnt[(w + 1) & 1];     // prev parity = (w-1)&1 = (w+1)&1
            for (int f = wv; f < fp; f += 7) {
                int o = flist[(w + 1) & 1][f];
                if (j < nw) {
                    unsigned long long g = gate[(size_t)o * 64 + j];
                    if (g) atomicOr(&supL[j], g);
                }
            }
        } else {
            // wave 0: resolve word w from LDS only
            int rem = Kc - (w << 6);
            unsigned long long maskw = (rem >= 64) ? ~0ull : ((1ull << rem) - 1ull);
            unsigned long long alive = ~(supL[w] | carry) & maskw;
            unsigned long long carry_next = 0ull;
            int myf = 0;
            while (alive) {
                int t = __builtin_ctzll(alive);
                int o = (w << 6) + t;
                if (tid == 0) {
                    if (nf < FIRE_CAP) fire_ord[nf] = o;
                    flist[w & 1][myf] = o;
                }
                ++nf; ++myf;
                unsigned long long dd0 = d0L[o];   // uniform LDS broadcast
                unsigned long long dd1 = d1L[o];
                alive &= ~(1ull << t);
                alive &= ~dd0;
                carry_next |= dd1;
            }
            if (tid == 0) fcnt[w & 1] = myf;
            carry = carry_next;
        }
        __syncthreads();   // prev-fire ORs + this word's flist visible for next word
    }
    if (tid == 0) fire_cnt[0] = nf < FIRE_CAP ? nf : FIRE_CAP;
}

// ---------------- finalize: recompute suppression vs fires, write output ----------------
__global__ __launch_bounds__(256) void finalize(const float* __restrict__ sboxes,
                                                const float* __restrict__ sareas,
                                                const float* __restrict__ scores,
                                                const int* __restrict__ order,
                                                const float4* __restrict__ cboxes,
                                                const float* __restrict__ carea,
                                                const int* __restrict__ cidx,
                                                const int* __restrict__ fire_ord,
                                                const int* __restrict__ fire_cnt,
                                                float* __restrict__ out) {
    __shared__ float4 FB[FIRE_CAP];
    __shared__ float FA[FIRE_CAP];
    __shared__ int FP[FIRE_CAP];
    int tid = threadIdx.x;
    int fc = fire_cnt[0];
    for (int k = tid; k < fc; k += 256) {
        int o = fire_ord[k];
        FB[k] = cboxes[o];
        FA[k] = carea[o];
        FP[k] = cidx[o];
    }
    __syncthreads();
    int j = blockIdx.x * 256 + tid;   // sorted index
    float4 b = ((const float4*)sboxes)[j];
    float aj = sareas[j];
    bool supp = false;
    for (int k = 0; k < fc; ++k) {
        float4 f = FB[k];
        float ix = fminf(b.z, f.z) - fmaxf(b.x, f.x);
        float iy = fminf(b.w, f.w) - fmaxf(b.y, f.y);
        float inter = fmaxf(ix, 0.f) * fmaxf(iy, 0.f);
        float denom = FA[k] + aj - inter;
        if (FP[k] < j && inter > 0.85f * denom) {
            if (inter / denom > IOU_THRF) supp = true;
        }
    }
    int n = order[j];
    float m = supp ? 0.f : 1.f;
    out[(size_t)n * 5 + 0] = b.x * m;
    out[(size_t)n * 5 + 1] = b.y * m;
    out[(size_t)n * 5 + 2] = b.z * m;
    out[(size_t)n * 5 + 3] = b.w * m;
    out[(size_t)n * 5 + 4] = scores[n] * m;
}

extern "C" void kernel_launch(void* const* d_in, const int* in_sizes, int n_in,
                              void* d_out, int out_size, void* d_ws, size_t ws_size,
                              hipStream_t stream) {
    const float* x      = (const float*)d_in[0];
    const float* anchors= (const float*)d_in[1];
    const float* dw_w   = (const float*)d_in[2];
    const float* pw_w   = (const float*)d_in[3];
    const float* bn1g   = (const float*)d_in[4];
    const float* bn1b   = (const float*)d_in[5];
    const float* bn1m   = (const float*)d_in[6];
    const float* bn1v   = (const float*)d_in[7];
    const float* anc_w  = (const float*)d_in[8];
    const float* ag     = (const float*)d_in[9];
    const float* ab     = (const float*)d_in[10];
    const float* am     = (const float*)d_in[11];
    const float* av     = (const float*)d_in[12];
    const float* obj_w  = (const float*)d_in[13];
    const float* og     = (const float*)d_in[14];
    const float* ob     = (const float*)d_in[15];
    const float* om     = (const float*)d_in[16];
    const float* ov     = (const float*)d_in[17];
    float* out = (float*)d_out;

    char* ws = (char*)d_ws;
    size_t off = 0;
    auto alloc = [&](size_t bytes) -> char* {
        char* p = ws + off;
        off = (off + bytes + 255) & ~(size_t)255;
        return p;
    };
    float* h0      = (float*)alloc(256 * 1024 * 4);
    float* h1      = (float*)alloc(256 * 1024 * 4);
    float* boxes   = (float*)alloc(NBOX * 4 * 4);
    float* scores  = (float*)alloc(NBOX * 4);
    unsigned* rank = (unsigned*)alloc(NBOX * 4);
    int* order     = (int*)alloc(NBOX * 4);
    float* sboxes  = (float*)alloc(NBOX * 4 * 4);
    float* sareas  = (float*)alloc(NBOX * 4);
    unsigned long long* rnz64 = (unsigned long long*)alloc(192 * 8);
    int* cidx      = (int*)alloc(CAND_CAP * 4);
    float4* cboxes = (float4*)alloc(CAND_CAP * 16);
    float* carea   = (float*)alloc(CAND_CAP * 4);
    int* knum      = (int*)alloc(256);
    int* fire_ord  = (int*)alloc(FIRE_CAP * 4);
    int* fire_cnt  = (int*)alloc(256);
    unsigned long long* gate  = (unsigned long long*)alloc((size_t)CAND_CAP * 64 * 8);
    unsigned long long* diag0 = (unsigned long long*)alloc(CAND_CAP * 8);
    unsigned long long* diag1 = (unsigned long long*)alloc(CAND_CAP * 8);

    hipMemsetAsync(rank, 0, NBOX * 4, stream);
    hipMemsetAsync(rnz64, 0, 192 * 8, stream);

    dw_conv<<<1024, 256, 0, stream>>>(x, dw_w, h0);
    pw_conv<<<dim3(4, 64), 256, 0, stream>>>(h0, pw_w, bn1g, bn1b, bn1m, bn1v, h1);
    heads<<<dim3(4, 45), 256, 0, stream>>>(h1, anc_w, ag, ab, am, av,
                                           obj_w, og, ob, om, ov, anchors, boxes, scores);
    rank_partial<<<dim3(36, 16), 256, 0, stream>>>(scores, rank);
    scatter_sorted<<<36, 256, 0, stream>>>(boxes, rank, order, sboxes, sareas);
    cand_detect<<<NTILES, 256, 0, stream>>>(sboxes, sareas, rnz64);
    compact_cand<<<1, 64, 0, stream>>>(rnz64, sboxes, sareas, cidx, cboxes, carea, knum);
    gate_build<<<CAND_CAP / 4, 256, 0, stream>>>(cboxes, carea, knum, gate, diag0, diag1);
    nms_scan5<<<1, 512, 0, stream>>>(gate, diag0, diag1, knum, fire_ord, fire_cnt);
    finalize<<<36, 256, 0, stream>>>(sboxes, sareas, scores, order,
                                     cboxes, carea, cidx, fire_ord, fire_cnt, out);
}

// Round 12
// 316.743 us; speedup vs baseline: 1.4073x; 1.1042x over previous
//
#include <hip/hip_runtime.h>
#include <hip/hip_bf16.h>

#define EPSF 1e-5f
#define IOU_THRF 0.9f
#define NBOX 9216
#define NWORDS 144   // 9216/64
#define CAND_CAP 4096
#define FIRE_CAP 1024
#define NTILES 666   // 36*37/2 upper-tri 256x256 tiles

// ---------------- depthwise 3x3 conv, C=256, 32x32, pad 1 ----------------
__global__ __launch_bounds__(256) void dw_conv(const float* __restrict__ x,
                                               const float* __restrict__ w,
                                               float* __restrict__ h0) {
    int idx = blockIdx.x * 256 + threadIdx.x;   // 262144 threads
    int c = idx >> 10, p = idx & 1023;
    int yy = p >> 5, xx = p & 31;
    const float* xi = x + (c << 10);
    const float* wc = w + c * 9;
    float acc = 0.f;
    #pragma unroll
    for (int dy = -1; dy <= 1; ++dy) {
        int y2 = yy + dy;
        if ((unsigned)y2 >= 32u) continue;
        #pragma unroll
        for (int dx = -1; dx <= 1; ++dx) {
            int x2 = xx + dx;
            if ((unsigned)x2 >= 32u) continue;
            acc += wc[(dy + 1) * 3 + (dx + 1)] * xi[y2 * 32 + x2];
        }
    }
    h0[idx] = acc;
}

// ---------------- pointwise 256x256 GEMM + BN1 + leaky relu ----------------
__global__ __launch_bounds__(256) void pw_conv(const float* __restrict__ h0,
                                               const float* __restrict__ w,
                                               const float* __restrict__ g,
                                               const float* __restrict__ b,
                                               const float* __restrict__ mu,
                                               const float* __restrict__ var,
                                               float* __restrict__ h1) {
    int p = blockIdx.x * 256 + threadIdx.x;
    int o0 = blockIdx.y * 4;
    float acc0 = 0.f, acc1 = 0.f, acc2 = 0.f, acc3 = 0.f;
    for (int c = 0; c < 256; ++c) {
        float hv = h0[(c << 10) + p];
        acc0 += w[(o0 + 0) * 256 + c] * hv;
        acc1 += w[(o0 + 1) * 256 + c] * hv;
        acc2 += w[(o0 + 2) * 256 + c] * hv;
        acc3 += w[(o0 + 3) * 256 + c] * hv;
    }
    float accs[4] = {acc0, acc1, acc2, acc3};
    #pragma unroll
    for (int k = 0; k < 4; ++k) {
        int o = o0 + k;
        float inv = 1.0f / sqrtf(var[o] + EPSF);
        float v = (accs[k] - mu[o]) * (inv * g[o]) + b[o];
        v = (v >= 0.f) ? v : 0.01f * v;
        h1[(o << 10) + p] = v;
    }
}

// ---------------- heads: anc (36 ch) + obj (9 ch) GEMV + BN + decode ----------------
__global__ __launch_bounds__(256) void heads(const float* __restrict__ h1,
                                             const float* __restrict__ anc_w,
                                             const float* __restrict__ ag,
                                             const float* __restrict__ ab,
                                             const float* __restrict__ am,
                                             const float* __restrict__ av,
                                             const float* __restrict__ obj_w,
                                             const float* __restrict__ og,
                                             const float* __restrict__ ob,
                                             const float* __restrict__ om,
                                             const float* __restrict__ ov,
                                             const float* __restrict__ anchors,
                                             float* __restrict__ boxes,
                                             float* __restrict__ scores) {
    int p = blockIdx.x * 256 + threadIdx.x;
    int o = blockIdx.y;
    const float* wrow = (o < 36) ? (anc_w + o * 256) : (obj_w + (o - 36) * 256);
    float acc = 0.f;
    for (int c = 0; c < 256; ++c) acc += wrow[c] * h1[(c << 10) + p];
    if (o < 36) {
        float inv = 1.0f / sqrtf(av[o] + EPSF);
        float v = (acc - am[o]) * (inv * ag[o]) + ab[o];
        v = fminf(fmaxf(v, 0.f), 6.f);           // clip 0..6
        int a = o >> 2, k = o & 3;
        float anch = anchors[a * 4 + k];
        float val = (k < 2) ? (v + anch) : (expf(v) * anch);
        boxes[(size_t)(a * 1024 + p) * 4 + k] = val;
    } else {
        int a = o - 36;
        float inv = 1.0f / sqrtf(ov[a] + EPSF);
        float v = (acc - om[a]) * (inv * og[a]) + ob[a];
        scores[a * 1024 + p] = 1.0f / (1.0f + expf(-v));
    }
}

// ---------------- rank = stable-descending-argsort position, O(N^2) count ----------------
// grid (36 n-blocks, 16 m-chunks of 576), 256 thr
__global__ __launch_bounds__(256) void rank_partial(const float* __restrict__ scores,
                                                    unsigned* __restrict__ rank) {
    __shared__ float4 sm[144];
    int mbase = blockIdx.y * 576;
    for (int t = threadIdx.x; t < 144; t += 256)
        sm[t] = ((const float4*)(scores + mbase))[t];
    __syncthreads();
    int n = blockIdx.x * 256 + threadIdx.x;
    float s = scores[n];
    unsigned cnt = 0;
    for (int q = 0; q < 144; ++q) {
        float4 v = sm[q];
        int m = mbase + q * 4;
        cnt += (v.x > s) || (v.x == s && (m + 0) < n);
        cnt += (v.y > s) || (v.y == s && (m + 1) < n);
        cnt += (v.z > s) || (v.z == s && (m + 2) < n);
        cnt += (v.w > s) || (v.w == s && (m + 3) < n);
    }
    atomicAdd(&rank[n], cnt);
}

// ---------------- scatter into sorted order ----------------
__global__ __launch_bounds__(256) void scatter_sorted(const float* __restrict__ boxes,
                                                      const unsigned* __restrict__ rank,
                                                      int* __restrict__ order,
                                                      float* __restrict__ sboxes,
                                                      float* __restrict__ sareas) {
    int n = blockIdx.x * 256 + threadIdx.x;
    unsigned r = rank[n];
    order[r] = n;
    float4 bx = ((const float4*)boxes)[n];
    ((float4*)sboxes)[r] = bx;
    sareas[r] = (bx.z - bx.x) * (bx.w - bx.y);
}

// ---------------- candidate detection over upper-tri 256x256 tiles ----------------
__global__ __launch_bounds__(256) void cand_detect(const float* __restrict__ sboxes,
                                                   const float* __restrict__ sareas,
                                                   unsigned long long* __restrict__ rnz64) {
    __shared__ float CX1[256], CY1[256], CX2[256], CY2[256], CAR[256];
    int rem = blockIdx.x, rb = 0;
    while (rem >= 36 - rb) { rem -= 36 - rb; ++rb; }
    int s = rb + rem;
    int tid = threadIdx.x;
    int i = rb * 256 + tid;
    {
        int j = s * 256 + tid;
        float4 cb = ((const float4*)sboxes)[j];
        CX1[tid] = cb.x; CY1[tid] = cb.y; CX2[tid] = cb.z; CY2[tid] = cb.w;
        CAR[tid] = sareas[j];
    }
    __syncthreads();
    float4 b = ((const float4*)sboxes)[i];
    float ar = sareas[i];
    bool any = false;

    if (s == rb) {
        for (int idx = tid + 1; idx < 256; ++idx) {
            float ix = fminf(b.z, CX2[idx]) - fmaxf(b.x, CX1[idx]);
            float iy = fminf(b.w, CY2[idx]) - fmaxf(b.y, CY1[idx]);
            float inter = fmaxf(ix, 0.f) * fmaxf(iy, 0.f);
            float denom = ar + CAR[idx] - inter;
            if (inter > 0.85f * denom) {
                if (inter / denom > IOU_THRF) any = true;
            }
        }
    } else {
        const float4* X1v = (const float4*)CX1;
        const float4* Y1v = (const float4*)CY1;
        const float4* X2v = (const float4*)CX2;
        const float4* Y2v = (const float4*)CY2;
        const float4* ARv = (const float4*)CAR;
        #pragma unroll 2
        for (int q = 0; q < 64; ++q) {
            float4 x1 = X1v[q], y1 = Y1v[q], x2 = X2v[q], y2 = Y2v[q], aa = ARv[q];
            #define CCHK(k) { \
                float ix = fminf(b.z, x2.k) - fmaxf(b.x, x1.k); \
                float iy = fminf(b.w, y2.k) - fmaxf(b.y, y1.k); \
                float inter = fmaxf(ix, 0.f) * fmaxf(iy, 0.f);  \
                float denom = ar + aa.k - inter;                \
                if (inter > 0.85f * denom) {                    \
                    if (inter / denom > IOU_THRF) any = true;   \
                } }
            CCHK(x) CCHK(y) CCHK(z) CCHK(w)
            #undef CCHK
        }
    }
    unsigned long long bal = __ballot(any);
    if ((tid & 63) == 0) atomicOr(&rnz64[rb * 4 + (tid >> 6)], bal);
}

__device__ inline unsigned long long rdl64(unsigned long long v, int l) {
    unsigned lo = (unsigned)__builtin_amdgcn_readlane((int)(unsigned)(v & 0xffffffffull), l);
    unsigned hi = (unsigned)__builtin_amdgcn_readlane((int)(unsigned)(v >> 32), l);
    return ((unsigned long long)hi << 32) | lo;
}

// ---------------- compact candidates, PARALLEL (36 blocks) ----------------
// pos = prefix_popcount(words < w) + popcount(bits below lane). Each block
// recomputes the 144-word prefix in LDS (Hillis-Steele), then 9216 threads
// gather/scatter independently — latency hidden by TLP.
__global__ __launch_bounds__(256) void compact_cand2(const unsigned long long* __restrict__ rnz64,
                                                     const float* __restrict__ sboxes,
                                                     const float* __restrict__ sareas,
                                                     int* __restrict__ cidx,
                                                     float4* __restrict__ cboxes,
                                                     float* __restrict__ carea,
                                                     int* __restrict__ knum) {
    __shared__ int incl[256];
    int tid = threadIdx.x;
    int myc = (tid < NWORDS) ? (int)__popcll(rnz64[tid]) : 0;
    incl[tid] = myc;
    __syncthreads();
    #pragma unroll
    for (int offd = 1; offd < 256; offd <<= 1) {
        int v = (tid >= offd) ? incl[tid - offd] : 0;
        __syncthreads();
        incl[tid] += v;
        __syncthreads();
    }
    if (blockIdx.x == 0 && tid == 0) {
        int tot = incl[NWORDS - 1];
        knum[0] = tot < CAND_CAP ? tot : CAND_CAP;
    }
    int i = blockIdx.x * 256 + tid;
    int w = i >> 6, l = i & 63;
    unsigned long long bits = rnz64[w];
    if (bits & (1ull << l)) {
        int base = incl[w] - (int)__popcll(bits);   // exclusive prefix of word w
        int pos = base + (int)__popcll(bits & ((1ull << l) - 1ull));
        if (pos < CAND_CAP) {
            cidx[pos] = i;
            cboxes[pos] = ((const float4*)sboxes)[i];
            carea[pos] = sareas[i];
        }
    }
}

// ---------------- candidate x candidate gating matrix + diagonal strips ----------------
__global__ __launch_bounds__(256) void gate_build(const float4* __restrict__ cboxes,
                                                  const float* __restrict__ carea,
                                                  const int* __restrict__ knum,
                                                  unsigned long long* __restrict__ gate,
                                                  unsigned long long* __restrict__ diag0,
                                                  unsigned long long* __restrict__ diag1) {
    int Kc = knum[0];
    int a = blockIdx.x * 4 + (threadIdx.x >> 6);
    int w = threadIdx.x & 63;
    if (a >= Kc) return;
    float4 b = cboxes[a];
    float ar = carea[a];
    unsigned long long bits = 0ull;
    int cbase = w * 64;
    if (cbase < Kc) {
        int lim = Kc - cbase; if (lim > 64) lim = 64;
        for (int t = 0; t < lim; ++t) {
            int c = cbase + t;
            if (c > a) {
                float4 cb = cboxes[c];
                float ix = fminf(b.z, cb.z) - fmaxf(b.x, cb.x);
                float iy = fminf(b.w, cb.w) - fmaxf(b.y, cb.y);
                float inter = fmaxf(ix, 0.f) * fmaxf(iy, 0.f);
                float denom = ar + carea[c] - inter;
                if (inter > 0.85f * denom) {
                    if (inter / denom > IOU_THRF) bits |= (1ull << t);
                }
            }
        }
    }
    gate[(size_t)a * 64 + w] = bits;
    int aw = a >> 6;
    if (w == aw) diag0[a] = bits;
    if (w == aw + 1) diag1[a] = bits;
}

// ---------------- serial greedy scan: LDS strips, lazy full-row OR ----------------
__global__ __launch_bounds__(512) void nms_scan5(const unsigned long long* __restrict__ gate,
                                                 const unsigned long long* __restrict__ diag0,
                                                 const unsigned long long* __restrict__ diag1,
                                                 const int* __restrict__ knum,
                                                 int* __restrict__ fire_ord,
                                                 int* __restrict__ fire_cnt) {
    __shared__ unsigned long long d0L[CAND_CAP];   // 32 KB
    __shared__ unsigned long long d1L[CAND_CAP];   // 32 KB
    __shared__ unsigned long long supL[64];
    __shared__ int flist[2][64];
    __shared__ int fcnt[2];
    int tid = threadIdx.x;
    int Kc = knum[0];
    int nw = (Kc + 63) >> 6;

    #pragma unroll
    for (int q = 0; q < CAND_CAP / 512; ++q) {
        d0L[tid + 512 * q] = diag0[tid + 512 * q];
        d1L[tid + 512 * q] = diag1[tid + 512 * q];
    }
    if (tid < 64) supL[tid] = 0ull;
    if (tid == 0) { fcnt[0] = 0; fcnt[1] = 0; }
    __syncthreads();

    int nf = 0;                       // wave0-uniform
    unsigned long long carry = 0ull;  // wave0-uniform

    for (int w = 0; w < nw; ++w) {
        if (tid >= 64) {
            int wv = (tid >> 6) - 1;        // 0..6
            int j = tid & 63;
            int fp = fcnt[(w + 1) & 1];
            for (int f = wv; f < fp; f += 7) {
                int o = flist[(w + 1) & 1][f];
                if (j < nw) {
                    unsigned long long g = gate[(size_t)o * 64 + j];
                    if (g) atomicOr(&supL[j], g);
                }
            }
        } else {
            int rem = Kc - (w << 6);
            unsigned long long maskw = (rem >= 64) ? ~0ull : ((1ull << rem) - 1ull);
            unsigned long long alive = ~(supL[w] | carry) & maskw;
            unsigned long long carry_next = 0ull;
            int myf = 0;
            while (alive) {
                int t = __builtin_ctzll(alive);
                int o = (w << 6) + t;
                if (tid == 0) {
                    if (nf < FIRE_CAP) fire_ord[nf] = o;
                    flist[w & 1][myf] = o;
                }
                ++nf; ++myf;
                unsigned long long dd0 = d0L[o];
                unsigned long long dd1 = d1L[o];
                alive &= ~(1ull << t);
                alive &= ~dd0;
                carry_next |= dd1;
            }
            if (tid == 0) fcnt[w & 1] = myf;
            carry = carry_next;
        }
        __syncthreads();
    }
    if (tid == 0) fire_cnt[0] = nf < FIRE_CAP ? nf : FIRE_CAP;
}

// ---------------- finalize: recompute suppression vs fires, write output ----------------
__global__ __launch_bounds__(256) void finalize(const float* __restrict__ sboxes,
                                                const float* __restrict__ sareas,
                                                const float* __restrict__ scores,
                                                const int* __restrict__ order,
                                                const float4* __restrict__ cboxes,
                                                const float* __restrict__ carea,
                                                const int* __restrict__ cidx,
                                                const int* __restrict__ fire_ord,
                                                const int* __restrict__ fire_cnt,
                                                float* __restrict__ out) {
    __shared__ float4 FB[FIRE_CAP];
    __shared__ float FA[FIRE_CAP];
    __shared__ int FP[FIRE_CAP];
    int tid = threadIdx.x;
    int fc = fire_cnt[0];
    for (int k = tid; k < fc; k += 256) {
        int o = fire_ord[k];
        FB[k] = cboxes[o];
        FA[k] = carea[o];
        FP[k] = cidx[o];
    }
    __syncthreads();
    int j = blockIdx.x * 256 + tid;   // sorted index
    float4 b = ((const float4*)sboxes)[j];
    float aj = sareas[j];
    bool supp = false;
    for (int k = 0; k < fc; ++k) {
        float4 f = FB[k];
        float ix = fminf(b.z, f.z) - fmaxf(b.x, f.x);
        float iy = fminf(b.w, f.w) - fmaxf(b.y, f.y);
        float inter = fmaxf(ix, 0.f) * fmaxf(iy, 0.f);
        float denom = FA[k] + aj - inter;
        if (FP[k] < j && inter > 0.85f * denom) {
            if (inter / denom > IOU_THRF) supp = true;
        }
    }
    int n = order[j];
    float m = supp ? 0.f : 1.f;
    out[(size_t)n * 5 + 0] = b.x * m;
    out[(size_t)n * 5 + 1] = b.y * m;
    out[(size_t)n * 5 + 2] = b.z * m;
    out[(size_t)n * 5 + 3] = b.w * m;
    out[(size_t)n * 5 + 4] = scores[n] * m;
}

extern "C" void kernel_launch(void* const* d_in, const int* in_sizes, int n_in,
                              void* d_out, int out_size, void* d_ws, size_t ws_size,
                              hipStream_t stream) {
    const float* x      = (const float*)d_in[0];
    const float* anchors= (const float*)d_in[1];
    const float* dw_w   = (const float*)d_in[2];
    const float* pw_w   = (const float*)d_in[3];
    const float* bn1g   = (const float*)d_in[4];
    const float* bn1b   = (const float*)d_in[5];
    const float* bn1m   = (const float*)d_in[6];
    const float* bn1v   = (const float*)d_in[7];
    const float* anc_w  = (const float*)d_in[8];
    const float* ag     = (const float*)d_in[9];
    const float* ab     = (const float*)d_in[10];
    const float* am     = (const float*)d_in[11];
    const float* av     = (const float*)d_in[12];
    const float* obj_w  = (const float*)d_in[13];
    const float* og     = (const float*)d_in[14];
    const float* ob     = (const float*)d_in[15];
    const float* om     = (const float*)d_in[16];
    const float* ov     = (const float*)d_in[17];
    float* out = (float*)d_out;

    char* ws = (char*)d_ws;
    size_t off = 0;
    auto alloc = [&](size_t bytes) -> char* {
        char* p = ws + off;
        off = (off + bytes + 255) & ~(size_t)255;
        return p;
    };
    float* h0      = (float*)alloc(256 * 1024 * 4);
    float* h1      = (float*)alloc(256 * 1024 * 4);
    float* boxes   = (float*)alloc(NBOX * 4 * 4);
    float* scores  = (float*)alloc(NBOX * 4);
    unsigned* rank = (unsigned*)alloc(NBOX * 4);
    int* order     = (int*)alloc(NBOX * 4);
    float* sboxes  = (float*)alloc(NBOX * 4 * 4);
    float* sareas  = (float*)alloc(NBOX * 4);
    unsigned long long* rnz64 = (unsigned long long*)alloc(192 * 8);
    int* cidx      = (int*)alloc(CAND_CAP * 4);
    float4* cboxes = (float4*)alloc(CAND_CAP * 16);
    float* carea   = (float*)alloc(CAND_CAP * 4);
    int* knum      = (int*)alloc(256);
    int* fire_ord  = (int*)alloc(FIRE_CAP * 4);
    int* fire_cnt  = (int*)alloc(256);
    unsigned long long* gate  = (unsigned long long*)alloc((size_t)CAND_CAP * 64 * 8);
    unsigned long long* diag0 = (unsigned long long*)alloc(CAND_CAP * 8);
    unsigned long long* diag1 = (unsigned long long*)alloc(CAND_CAP * 8);

    hipMemsetAsync(rank, 0, NBOX * 4, stream);
    hipMemsetAsync(rnz64, 0, 192 * 8, stream);

    dw_conv<<<1024, 256, 0, stream>>>(x, dw_w, h0);
    pw_conv<<<dim3(4, 64), 256, 0, stream>>>(h0, pw_w, bn1g, bn1b, bn1m, bn1v, h1);
    heads<<<dim3(4, 45), 256, 0, stream>>>(h1, anc_w, ag, ab, am, av,
                                           obj_w, og, ob, om, ov, anchors, boxes, scores);
    rank_partial<<<dim3(36, 16), 256, 0, stream>>>(scores, rank);
    scatter_sorted<<<36, 256, 0, stream>>>(boxes, rank, order, sboxes, sareas);
    cand_detect<<<NTILES, 256, 0, stream>>>(sboxes, sareas, rnz64);
    compact_cand2<<<36, 256, 0, stream>>>(rnz64, sboxes, sareas, cidx, cboxes, carea, knum);
    gate_build<<<CAND_CAP / 4, 256, 0, stream>>>(cboxes, carea, knum, gate, diag0, diag1);
    nms_scan5<<<1, 512, 0, stream>>>(gate, diag0, diag1, knum, fire_ord, fire_cnt);
    finalize<<<36, 256, 0, stream>>>(sboxes, sareas, scores, order,
                                     cboxes, carea, cidx, fire_ord, fire_cnt, out);
}